// Round 7
// baseline (575.920 us; speedup 1.0000x reference)
//
#include <hip/hip_runtime.h>
#include <hip/hip_bf16.h>
#include <math.h>

#define HID 128
#define LDA 136   // bf16 LDS row stride (shorts); 272B rows, 16B aligned
#define POOL_P 4

typedef __attribute__((ext_vector_type(8))) short bf16x8;
typedef __attribute__((ext_vector_type(4))) float f32x4;

__device__ __forceinline__ short f2bf(float f) {
    unsigned int u = __float_as_uint(f);
    u += 0x7FFF + ((u >> 16) & 1);   // RNE
    return (short)(u >> 16);
}
__device__ __forceinline__ float bf2f(short s) {
    return __uint_as_float(((unsigned int)(unsigned short)s) << 16);
}

// ------- fused front-end: blocks [0,nEmb) embed; rest histogram dst + record rank -------
__global__ __launch_bounds__(256) void embed_hist_k(const int* __restrict__ x,
                                                    const float* __restrict__ emb,
                                                    short* __restrict__ h, int nnodes,
                                                    const int* __restrict__ dst,
                                                    int* __restrict__ deg,
                                                    int* __restrict__ rank_arr,
                                                    int nedges, int nEmb) {
    if ((int)blockIdx.x < nEmb) {
        int tid = blockIdx.x * 256 + threadIdx.x;
        int node = tid >> 4;
        int c8 = tid & 15;
        if (node >= nnodes) return;
        int tok = x[node];
        float4 f0 = ((const float4*)emb)[(size_t)tok * 32 + c8 * 2];
        float4 f1 = ((const float4*)emb)[(size_t)tok * 32 + c8 * 2 + 1];
        bf16x8 o;
        o[0] = f2bf(f0.x); o[1] = f2bf(f0.y); o[2] = f2bf(f0.z); o[3] = f2bf(f0.w);
        o[4] = f2bf(f1.x); o[5] = f2bf(f1.y); o[6] = f2bf(f1.z); o[7] = f2bf(f1.w);
        *(bf16x8*)(h + (size_t)node * HID + c8 * 8) = o;
    } else {
        int e = (blockIdx.x - nEmb) * 256 + threadIdx.x;
        if (e < nedges) {
            int d = __builtin_nontemporal_load(&dst[e]);
            int r = atomicAdd(&deg[d], 1);   // rank of edge e within its dst bucket
            rank_arr[e] = r;                  // sequential coalesced write
        }
    }
}

// decoupled-lookback exclusive scan: 25 blocks x 4096 elems (requires blocks <= 64).
// Aggregates/flags via device-scope atomics (bflag pre-zeroed by memset).
__global__ __launch_bounds__(1024) void scan_k(const int* __restrict__ deg,
                                               int* __restrict__ rowstart,
                                               int n, int* bsum, int* bflag, int nblocks) {
    __shared__ int wsum[16];
    __shared__ int prefix_s, total_s;
    const int b = blockIdx.x;
    const int t = threadIdx.x, lane = t & 63, w = t >> 6;
    const int i4 = b * 4096 + t * 4;
    int4 v = make_int4(0, 0, 0, 0);
    if (i4 + 3 < n) v = *(const int4*)(deg + i4);
    else if (i4 < n) {
        v.x = deg[i4];
        if (i4 + 1 < n) v.y = deg[i4 + 1];
        if (i4 + 2 < n) v.z = deg[i4 + 2];
    }
    int s1 = v.x + v.y, s2 = s1 + v.z, s3 = s2 + v.w;
    int sum = s3;
    #pragma unroll
    for (int off = 1; off < 64; off <<= 1) {
        int o = __shfl_up(sum, off, 64);
        if (lane >= off) sum += o;
    }
    if (lane == 63) wsum[w] = sum;
    __syncthreads();
    if (t == 0) {
        int run = 0;
        #pragma unroll
        for (int k = 0; k < 16; ++k) { int xx = wsum[k]; wsum[k] = run; run += xx; }
        total_s = run;
        // publish aggregate (device-scope so all XCDs see it)
        atomicExch(&bsum[b], run);
        __threadfence();
        atomicExch(&bflag[b], 1);
    }
    __syncthreads();
    // parallel lookback: lane i waits for block i's aggregate (i < b)
    if (w == 0) {
        int p = 0;
        if (lane < b) {
            while (atomicAdd(&bflag[lane], 0) == 0) {}
            p = atomicAdd(&bsum[lane], 0);
        }
        #pragma unroll
        for (int off = 32; off >= 1; off >>= 1) p += __shfl_down(p, off, 64);
        if (lane == 0) prefix_s = p;
    }
    __syncthreads();
    const int excl = (sum - s3) + wsum[w] + prefix_s;
    if (i4 + 3 < n) {
        *(int4*)(rowstart + i4) = make_int4(excl, excl + v.x, excl + s1, excl + s2);
    } else if (i4 < n) {
        rowstart[i4] = excl;
        if (i4 + 1 < n) rowstart[i4 + 1] = excl + v.x;
        if (i4 + 2 < n) rowstart[i4 + 2] = excl + s1;
    }
    if (b == nblocks - 1 && t == 1023) rowstart[n] = prefix_s + total_s;
}

// XCD-partitioned, atomic-free bucket fill: pos = rowstart[d] + rank[e].
__global__ __launch_bounds__(256) void fill_k(const int* __restrict__ src,
                                              const int* __restrict__ dst,
                                              const int* __restrict__ rank_arr,
                                              const int* __restrict__ rowstart,
                                              int* __restrict__ sorted_src,
                                              int nedges, int npp, int nnodes, int nch) {
    const int part = blockIdx.x & 7;
    const int chunk = blockIdx.x >> 3;
    const int lo = part * npp;
    const int hi = min(lo + npp, nnodes);
    const int stride = nch * 256;
    for (int e = chunk * 256 + threadIdx.x; e < nedges; e += stride) {
        int d = __builtin_nontemporal_load(&dst[e]);
        if (d >= lo && d < hi) {
            int s = src[e];           // L3-resident after first pass
            int r = rank_arr[e];
            sorted_src[rowstart[d] + r] = s;
        }
    }
}

// ---------------- gather-aggregate (bf16 h), 4-deep MLP ----------------
__global__ __launch_bounds__(256) void gather_k(const int* __restrict__ rowstart,
                                                const int* __restrict__ sorted_src,
                                                const short* __restrict__ h,
                                                short* __restrict__ agg, int nnodes) {
    int tid = blockIdx.x * 256 + threadIdx.x;
    int node = tid >> 4;
    int l = tid & 15;
    if (node >= nnodes) return;
    int beg = rowstart[node];
    int end = rowstart[node + 1];
    const bf16x8* hr = (const bf16x8*)h;
    float a[8];
    #pragma unroll
    for (int i = 0; i < 8; ++i) a[i] = 0.f;
    int e = beg;
    for (; e + 4 <= end; e += 4) {
        int s0 = sorted_src[e];
        int s1 = sorted_src[e + 1];
        int s2 = sorted_src[e + 2];
        int s3 = sorted_src[e + 3];
        bf16x8 v0 = hr[(size_t)s0 * 16 + l];
        bf16x8 v1 = hr[(size_t)s1 * 16 + l];
        bf16x8 v2 = hr[(size_t)s2 * 16 + l];
        bf16x8 v3 = hr[(size_t)s3 * 16 + l];
        #pragma unroll
        for (int i = 0; i < 8; ++i) a[i] += bf2f(v0[i]);
        #pragma unroll
        for (int i = 0; i < 8; ++i) a[i] += bf2f(v1[i]);
        #pragma unroll
        for (int i = 0; i < 8; ++i) a[i] += bf2f(v2[i]);
        #pragma unroll
        for (int i = 0; i < 8; ++i) a[i] += bf2f(v3[i]);
    }
    for (; e < end; ++e) {
        bf16x8 v0 = hr[(size_t)sorted_src[e] * 16 + l];
        #pragma unroll
        for (int i = 0; i < 8; ++i) a[i] += bf2f(v0[i]);
    }
    bf16x8 o;
    #pragma unroll
    for (int i = 0; i < 8; ++i) o[i] = f2bf(a[i]);
    *(bf16x8*)(agg + (size_t)node * HID + l * 8) = o;
}

// ---------------- weight pack: all three weight sets in one launch ----------------
__global__ __launch_bounds__(256) void pack_all_k(const float* __restrict__ Wih0,
                                                  const float* __restrict__ Whh0,
                                                  const float* __restrict__ Wih1,
                                                  const float* __restrict__ Whh1,
                                                  const float* __restrict__ dW,
                                                  short* __restrict__ P0,
                                                  short* __restrict__ P1,
                                                  short* __restrict__ Pd) {
    int b = blockIdx.x;
    const float* WA; const float* WB; short* P; int ntilesA; int tile;
    if (b < 48)      { WA = Wih0; WB = Whh0; P = P0; ntilesA = 24; tile = b; }
    else if (b < 96) { WA = Wih1; WB = Whh1; P = P1; ntilesA = 24; tile = b - 48; }
    else             { WA = dW;   WB = dW;   P = Pd; ntilesA = 8;  tile = b - 96; }
    const int t = threadIdx.x;
    const int lane = t & 63, k0 = t >> 6;
    const float* W;
    int row;
    if (tile < ntilesA) { W = WA; row = tile * 16 + (lane & 15); }
    else                { W = WB; row = (tile - ntilesA) * 16 + (lane & 15); }
    const int k = k0 * 32 + (lane >> 4) * 8;
    const float4 f0 = *(const float4*)(W + row * HID + k);
    const float4 f1 = *(const float4*)(W + row * HID + k + 4);
    short4 o0 = make_short4(f2bf(f0.x), f2bf(f0.y), f2bf(f0.z), f2bf(f0.w));
    short4 o1 = make_short4(f2bf(f1.x), f2bf(f1.y), f2bf(f1.z), f2bf(f1.w));
    short* dstp = P + ((size_t)(tile * 4 + k0) * 64 + lane) * 8;
    *(short4*)(dstp) = o0;
    *(short4*)(dstp + 4) = o1;
}

// ---------------- MFMA GRU cell, 32-row tile (bf16 in/out) ----------------
__global__ __launch_bounds__(256) void gru_mfma_k(const short* __restrict__ agg,
                                                  const short* __restrict__ hin,
                                                  short* __restrict__ hout,
                                                  const short* __restrict__ P,
                                                  const float* __restrict__ bih,
                                                  const float* __restrict__ bhh,
                                                  int nnodes) {
    __shared__ short As[32 * LDA];
    __shared__ short Hs[32 * LDA];
    const int t = threadIdx.x;
    const int mbase = blockIdx.x * 32;
    #pragma unroll
    for (int half = 0; half < 2; ++half) {
        int row = (t >> 4) + half * 16;
        int c8 = t & 15;
        int node = mbase + row;
        bf16x8 a = (bf16x8){0,0,0,0,0,0,0,0};
        bf16x8 hh = (bf16x8){0,0,0,0,0,0,0,0};
        if (node < nnodes) {
            a  = *(const bf16x8*)(agg + (size_t)node * HID + c8 * 8);
            hh = *(const bf16x8*)(hin + (size_t)node * HID + c8 * 8);
        }
        *(bf16x8*)&As[row * LDA + c8 * 8] = a;
        *(bf16x8*)&Hs[row * LDA + c8 * 8] = hh;
    }
    __syncthreads();

    const int w = t >> 6, lane = t & 63;
    const int ml = lane & 15, kq = lane >> 4;
    const int j0 = w * 32;

    f32x4 acc[24];  // [((m*3+g)*2+ctt)*2 + rt]
    #pragma unroll
    for (int i = 0; i < 24; ++i) acc[i] = (f32x4){0.f, 0.f, 0.f, 0.f};

    const short* Pb = P + (size_t)lane * 8;

    #pragma unroll
    for (int k0 = 0; k0 < 4; ++k0) {
        bf16x8 aa0 = *(const bf16x8*)&As[ml * LDA + k0 * 32 + kq * 8];
        bf16x8 aa1 = *(const bf16x8*)&As[(16 + ml) * LDA + k0 * 32 + kq * 8];
        bf16x8 ah0 = *(const bf16x8*)&Hs[ml * LDA + k0 * 32 + kq * 8];
        bf16x8 ah1 = *(const bf16x8*)&Hs[(16 + ml) * LDA + k0 * 32 + kq * 8];
        #pragma unroll
        for (int m = 0; m < 2; ++m) {
            #pragma unroll
            for (int g = 0; g < 3; ++g) {
                #pragma unroll
                for (int ctt = 0; ctt < 2; ++ctt) {
                    const int tile = m * 24 + g * 8 + (w << 1) + ctt;
                    bf16x8 bb = *(const bf16x8*)(Pb + (size_t)(tile * 4 + k0) * 512);
                    const int idx = ((m * 3 + g) * 2 + ctt) * 2;
                    acc[idx]     = __builtin_amdgcn_mfma_f32_16x16x32_bf16(
                        (m == 0) ? aa0 : ah0, bb, acc[idx], 0, 0, 0);
                    acc[idx + 1] = __builtin_amdgcn_mfma_f32_16x16x32_bf16(
                        (m == 0) ? aa1 : ah1, bb, acc[idx + 1], 0, 0, 0);
                }
            }
        }
    }

    #pragma unroll
    for (int ctt = 0; ctt < 2; ++ctt) {
        const int col = j0 + ctt * 16 + ml;
        const float b_ir = bih[col], b_iz = bih[col + 128], b_in = bih[col + 256];
        const float b_hr = bhh[col], b_hz = bhh[col + 128], b_hn = bhh[col + 256];
        #pragma unroll
        for (int rt = 0; rt < 2; ++rt) {
            #pragma unroll
            for (int r = 0; r < 4; ++r) {
                const int row = rt * 16 + kq * 4 + r;
                const int node = mbase + row;
                float ir = acc[(0 * 2 + ctt) * 2 + rt][r] + b_ir;
                float iz = acc[(1 * 2 + ctt) * 2 + rt][r] + b_iz;
                float in_ = acc[(2 * 2 + ctt) * 2 + rt][r] + b_in;
                float hr = acc[(3 * 2 + ctt) * 2 + rt][r] + b_hr;
                float hz = acc[(4 * 2 + ctt) * 2 + rt][r] + b_hz;
                float hn = acc[(5 * 2 + ctt) * 2 + rt][r] + b_hn;
                float rr = 1.f / (1.f + expf(-(ir + hr)));
                float z  = 1.f / (1.f + expf(-(iz + hz)));
                float n  = tanhf(in_ + rr * hn);
                if (node < nnodes) {
                    float hval = bf2f(Hs[row * LDA + col]);
                    hout[(size_t)node * HID + col] = f2bf((1.f - z) * n + z * hval);
                }
            }
        }
    }
}

// ------- layer-1 GRU fused with dense: h' never leaves the block (LDS round-trip) -------
__global__ __launch_bounds__(256) void gru_dense_k(const short* __restrict__ agg,
                                                   const short* __restrict__ hin,
                                                   short* __restrict__ yout,
                                                   const short* __restrict__ P,
                                                   const float* __restrict__ bih,
                                                   const float* __restrict__ bhh,
                                                   const short* __restrict__ Pd,
                                                   const float* __restrict__ db,
                                                   int nnodes) {
    __shared__ short As[32 * LDA];
    __shared__ short Hs[32 * LDA];
    const int t = threadIdx.x;
    const int mbase = blockIdx.x * 32;
    #pragma unroll
    for (int half = 0; half < 2; ++half) {
        int row = (t >> 4) + half * 16;
        int c8 = t & 15;
        int node = mbase + row;
        bf16x8 a = (bf16x8){0,0,0,0,0,0,0,0};
        bf16x8 hh = (bf16x8){0,0,0,0,0,0,0,0};
        if (node < nnodes) {
            a  = *(const bf16x8*)(agg + (size_t)node * HID + c8 * 8);
            hh = *(const bf16x8*)(hin + (size_t)node * HID + c8 * 8);
        }
        *(bf16x8*)&As[row * LDA + c8 * 8] = a;
        *(bf16x8*)&Hs[row * LDA + c8 * 8] = hh;
    }
    __syncthreads();

    const int w = t >> 6, lane = t & 63;
    const int ml = lane & 15, kq = lane >> 4;
    const int j0 = w * 32;

    f32x4 acc[24];
    #pragma unroll
    for (int i = 0; i < 24; ++i) acc[i] = (f32x4){0.f, 0.f, 0.f, 0.f};

    const short* Pb = P + (size_t)lane * 8;

    #pragma unroll
    for (int k0 = 0; k0 < 4; ++k0) {
        bf16x8 aa0 = *(const bf16x8*)&As[ml * LDA + k0 * 32 + kq * 8];
        bf16x8 aa1 = *(const bf16x8*)&As[(16 + ml) * LDA + k0 * 32 + kq * 8];
        bf16x8 ah0 = *(const bf16x8*)&Hs[ml * LDA + k0 * 32 + kq * 8];
        bf16x8 ah1 = *(const bf16x8*)&Hs[(16 + ml) * LDA + k0 * 32 + kq * 8];
        #pragma unroll
        for (int m = 0; m < 2; ++m) {
            #pragma unroll
            for (int g = 0; g < 3; ++g) {
                #pragma unroll
                for (int ctt = 0; ctt < 2; ++ctt) {
                    const int tile = m * 24 + g * 8 + (w << 1) + ctt;
                    bf16x8 bb = *(const bf16x8*)(Pb + (size_t)(tile * 4 + k0) * 512);
                    const int idx = ((m * 3 + g) * 2 + ctt) * 2;
                    acc[idx]     = __builtin_amdgcn_mfma_f32_16x16x32_bf16(
                        (m == 0) ? aa0 : ah0, bb, acc[idx], 0, 0, 0);
                    acc[idx + 1] = __builtin_amdgcn_mfma_f32_16x16x32_bf16(
                        (m == 0) ? aa1 : ah1, bb, acc[idx + 1], 0, 0, 0);
                }
            }
        }
    }

    // GRU epilogue -> h' kept in registers
    short hnew[2][2][4];   // [ctt][rt][r]
    #pragma unroll
    for (int ctt = 0; ctt < 2; ++ctt) {
        const int col = j0 + ctt * 16 + ml;
        const float b_ir = bih[col], b_iz = bih[col + 128], b_in = bih[col + 256];
        const float b_hr = bhh[col], b_hz = bhh[col + 128], b_hn = bhh[col + 256];
        #pragma unroll
        for (int rt = 0; rt < 2; ++rt) {
            #pragma unroll
            for (int r = 0; r < 4; ++r) {
                const int row = rt * 16 + kq * 4 + r;
                float ir = acc[(0 * 2 + ctt) * 2 + rt][r] + b_ir;
                float iz = acc[(1 * 2 + ctt) * 2 + rt][r] + b_iz;
                float in_ = acc[(2 * 2 + ctt) * 2 + rt][r] + b_in;
                float hr = acc[(3 * 2 + ctt) * 2 + rt][r] + b_hr;
                float hz = acc[(4 * 2 + ctt) * 2 + rt][r] + b_hz;
                float hn = acc[(5 * 2 + ctt) * 2 + rt][r] + b_hn;
                float rr = 1.f / (1.f + expf(-(ir + hr)));
                float z  = 1.f / (1.f + expf(-(iz + hz)));
                float n  = tanhf(in_ + rr * hn);
                float hval = bf2f(Hs[row * LDA + col]);
                hnew[ctt][rt][r] = f2bf((1.f - z) * n + z * hval);
            }
        }
    }

    __syncthreads();   // all waves done reading As/Hs for MFMA+epilogue
    #pragma unroll
    for (int ctt = 0; ctt < 2; ++ctt) {
        const int col = j0 + ctt * 16 + ml;
        #pragma unroll
        for (int rt = 0; rt < 2; ++rt) {
            #pragma unroll
            for (int r = 0; r < 4; ++r) {
                const int row = rt * 16 + kq * 4 + r;
                As[row * LDA + col] = hnew[ctt][rt][r];   // h' tile, row-major
            }
        }
    }
    __syncthreads();

    // dense phase: y = h' @ dW.T + db
    f32x4 dacc[4];  // [ctt*2+rt]
    #pragma unroll
    for (int i = 0; i < 4; ++i) dacc[i] = (f32x4){0.f, 0.f, 0.f, 0.f};
    const short* Pbd = Pd + (size_t)lane * 8;
    #pragma unroll
    for (int k0 = 0; k0 < 4; ++k0) {
        bf16x8 aa0 = *(const bf16x8*)&As[ml * LDA + k0 * 32 + kq * 8];
        bf16x8 aa1 = *(const bf16x8*)&As[(16 + ml) * LDA + k0 * 32 + kq * 8];
        #pragma unroll
        for (int ctt = 0; ctt < 2; ++ctt) {
            const int tile = (w << 1) + ctt;
            bf16x8 bb = *(const bf16x8*)(Pbd + (size_t)(tile * 4 + k0) * 512);
            dacc[ctt * 2]     = __builtin_amdgcn_mfma_f32_16x16x32_bf16(aa0, bb, dacc[ctt * 2], 0, 0, 0);
            dacc[ctt * 2 + 1] = __builtin_amdgcn_mfma_f32_16x16x32_bf16(aa1, bb, dacc[ctt * 2 + 1], 0, 0, 0);
        }
    }
    #pragma unroll
    for (int ctt = 0; ctt < 2; ++ctt) {
        const int col = j0 + ctt * 16 + ml;
        const float bias = db[col];
        #pragma unroll
        for (int rt = 0; rt < 2; ++rt) {
            #pragma unroll
            for (int r = 0; r < 4; ++r) {
                const int node = mbase + rt * 16 + kq * 4 + r;
                if (node < nnodes)
                    yout[(size_t)node * HID + col] = f2bf(dacc[ctt * 2 + rt][r] + bias);
            }
        }
    }
}

// ---------------- segment max pool, 4-way split per graph ----------------
__global__ __launch_bounds__(256) void pool_k(const short* __restrict__ xh,
                                              const int* __restrict__ batch,
                                              int nnodes, float* __restrict__ pmax) {
    const int g = blockIdx.x >> 2;
    const int p = blockIdx.x & (POOL_P - 1);
    int lo = 0, hi = nnodes;
    while (lo < hi) { int mid = (lo + hi) >> 1; if (batch[mid] < g) lo = mid + 1; else hi = mid; }
    int start = lo;
    lo = 0; hi = nnodes;
    while (lo < hi) { int mid = (lo + hi) >> 1; if (batch[mid] < g + 1) lo = mid + 1; else hi = mid; }
    int end = lo;
    int len = end - start;
    int q0 = start + (int)(((long long)len * p) / POOL_P);
    int q1 = start + (int)(((long long)len * (p + 1)) / POOL_P);

    const int rg = threadIdx.x >> 6;
    const int j2 = threadIdx.x & 63;
    float m0 = -INFINITY, m1 = -INFINITY;
    for (int i = q0 + rg; i < q1; i += 4) {
        unsigned int u = *(const unsigned int*)(xh + (size_t)i * HID + j2 * 2);
        m0 = fmaxf(m0, __uint_as_float(u << 16));
        m1 = fmaxf(m1, __uint_as_float(u & 0xFFFF0000u));
    }
    __shared__ float pm[4][130];
    pm[rg][j2 * 2] = m0;
    pm[rg][j2 * 2 + 1] = m1;
    __syncthreads();
    if (rg == 0) {
        float a = fmaxf(fmaxf(pm[0][j2 * 2], pm[1][j2 * 2]), fmaxf(pm[2][j2 * 2], pm[3][j2 * 2]));
        float c = fmaxf(fmaxf(pm[0][j2 * 2 + 1], pm[1][j2 * 2 + 1]), fmaxf(pm[2][j2 * 2 + 1], pm[3][j2 * 2 + 1]));
        *(float2*)(pmax + (size_t)blockIdx.x * HID + j2 * 2) = make_float2(a, c);
    }
}

// ---------------- classifier: reduce partial maxes, dot, sigmoid ----------------
__global__ __launch_bounds__(128) void clf_k(const float* __restrict__ pmax,
                                             const float* __restrict__ W,
                                             const float* __restrict__ b,
                                             float* __restrict__ out) {
    __shared__ float red[2];
    const int g = blockIdx.x;
    const int t = threadIdx.x;
    float m = -INFINITY;
    #pragma unroll
    for (int p = 0; p < POOL_P; ++p)
        m = fmaxf(m, pmax[((size_t)g * POOL_P + p) * HID + t]);
    float v = m * W[t];
    #pragma unroll
    for (int off = 32; off >= 1; off >>= 1) v += __shfl_down(v, off, 64);
    if ((t & 63) == 0) red[t >> 6] = v;
    __syncthreads();
    if (t == 0) {
        float s = red[0] + red[1] + b[0];
        out[g] = 1.f / (1.f + expf(-s));
    }
}

extern "C" void kernel_launch(void* const* d_in, const int* in_sizes, int n_in,
                              void* d_out, int out_size, void* d_ws, size_t ws_size,
                              hipStream_t stream) {
    const int* x      = (const int*)d_in[0];
    const int* ei     = (const int*)d_in[1];
    const int* batch  = (const int*)d_in[2];
    const float* emb  = (const float*)d_in[3];
    const float* Wih0 = (const float*)d_in[4];
    const float* Whh0 = (const float*)d_in[5];
    const float* bih0 = (const float*)d_in[6];
    const float* bhh0 = (const float*)d_in[7];
    const float* Wih1 = (const float*)d_in[8];
    const float* Whh1 = (const float*)d_in[9];
    const float* bih1 = (const float*)d_in[10];
    const float* bhh1 = (const float*)d_in[11];
    const float* dW   = (const float*)d_in[12];
    const float* db   = (const float*)d_in[13];
    const float* cW   = (const float*)d_in[14];
    const float* cb   = (const float*)d_in[15];

    const int N = in_sizes[0];          // 100000
    const int E = in_sizes[1] / 2;      // 1600000
    const int NG = out_size;            // 128
    const size_t NH = (size_t)N * HID;

    short* hb0 = (short*)d_ws;                       // NH bf16
    short* hb1 = hb0 + NH;                           // NH bf16 (agg)
    short* hb2 = hb1 + NH;                           // NH bf16
    short* P0  = hb2 + NH;                           // 48*4*64*8
    short* P1  = P0 + 48 * 4 * 64 * 8;
    short* Pd  = P1 + 48 * 4 * 64 * 8;               // 8*4*64*8
    float* pmax = (float*)(Pd + 8 * 4 * 64 * 8);     // NG*POOL_P*HID
    int* deg        = (int*)(pmax + (size_t)NG * POOL_P * HID);  // N
    int* bflag      = deg + N;                       // 32 (zeroed w/ deg)
    int* bsum       = bflag + 32;                    // 32
    int* rowstart   = bsum + 32;                     // N+4
    int* rank_arr   = rowstart + (N + 4);            // E
    int* sorted_src = rank_arr + E;                  // E

    const int* esrc = ei;
    const int* edst = ei + E;

    dim3 blk(256);
    int embGrid  = (N * 16 + 255) / 256;
    int edgeGrid = (E + 255) / 256;
    int tileGrid = (N + 31) / 32;
    const int NCH = 104;                      // fill chunks/partition
    const int scanBlocks = (N + 4095) / 4096; // must be <= 64 (one-wave lookback)

    // weight packing (one launch, independent of data path)
    pack_all_k<<<104, blk, 0, stream>>>(Wih0, Whh0, Wih1, Whh1, dW, P0, P1, Pd);

    // embed + dst-histogram(+rank) fused
    hipMemsetAsync(deg, 0, (size_t)(N + 32) * sizeof(int), stream);
    embed_hist_k<<<embGrid + edgeGrid, blk, 0, stream>>>(x, emb, hb0, N,
                                                         edst, deg, rank_arr, E, embGrid);

    // CSR: lookback scan + atomic-free fill
    scan_k<<<scanBlocks, dim3(1024), 0, stream>>>(deg, rowstart, N, bsum, bflag, scanBlocks);
    fill_k<<<8 * NCH, blk, 0, stream>>>(esrc, edst, rank_arr, rowstart, sorted_src,
                                        E, (N + 7) / 8, N, NCH);

    // layer 0
    gather_k<<<embGrid, blk, 0, stream>>>(rowstart, sorted_src, hb0, hb1, N);
    gru_mfma_k<<<tileGrid, blk, 0, stream>>>(hb1, hb0, hb2, P0, bih0, bhh0, N);

    // layer 1 (+ dense fused; h1 never hits global)
    gather_k<<<embGrid, blk, 0, stream>>>(rowstart, sorted_src, hb2, hb1, N);
    gru_dense_k<<<tileGrid, blk, 0, stream>>>(hb1, hb2, hb0, P1, bih1, bhh1, Pd, db, N);

    // pool + classifier
    pool_k<<<NG * POOL_P, blk, 0, stream>>>(hb0, batch, N, pmax);
    clf_k<<<NG, dim3(128), 0, stream>>>(pmax, cW, cb, (float*)d_out);
}

// Round 8
// 566.723 us; speedup vs baseline: 1.0162x; 1.0162x over previous
//
#include <hip/hip_runtime.h>
#include <hip/hip_bf16.h>
#include <math.h>

#define HID 128
#define LDA 136   // bf16 LDS row stride (shorts)
#define POOL_P 4
#define NPART 8
#define NCHUNK 32
#define MAXBIN 12544   // LDS bins per partition (>= ceil(N/8)); 50.2 KB

typedef __attribute__((ext_vector_type(8))) short bf16x8;
typedef __attribute__((ext_vector_type(4))) float f32x4;
typedef __attribute__((ext_vector_type(4))) int int4v;

__device__ __forceinline__ short f2bf(float f) {
    unsigned int u = __float_as_uint(f);
    u += 0x7FFF + ((u >> 16) & 1);   // RNE
    return (short)(u >> 16);
}
__device__ __forceinline__ float bf2f(short s) {
    return __uint_as_float(((unsigned int)(unsigned short)s) << 16);
}

// ------- fused: blocks [0,256) build per-(part,chunk) LDS histograms; rest embed -------
__global__ __launch_bounds__(256) void radix_embed_k(const int* __restrict__ x,
                                                     const float* __restrict__ emb,
                                                     short* __restrict__ h, int nnodes,
                                                     const int* __restrict__ dst,
                                                     int* __restrict__ ghist,
                                                     int nedges, int NPB, int ECH) {
    __shared__ int lh[MAXBIN];
    if ((int)blockIdx.x < NPART * NCHUNK) {
        const int part = blockIdx.x & (NPART - 1);
        const int chunk = blockIdx.x >> 3;          // /NPART
        const int lo = part * NPB;
        const int hi = min(lo + NPB, nnodes);
        const int nb = hi - lo;
        for (int b = threadIdx.x; b < nb; b += 256) lh[b] = 0;
        __syncthreads();
        const int e0 = chunk * ECH;
        const int e1 = min(nedges, e0 + ECH);
        for (int base = e0; base < e1; base += 1024) {
            int e = base + (threadIdx.x << 2);
            if (e + 4 <= e1) {
                int4v d4 = __builtin_nontemporal_load((const int4v*)(dst + e));
                #pragma unroll
                for (int k = 0; k < 4; ++k) {
                    int d = d4[k];
                    if (d >= lo && d < hi) atomicAdd(&lh[d - lo], 1);
                }
            } else {
                for (int k = 0; k < 4 && e + k < e1; ++k) {
                    int d = __builtin_nontemporal_load(&dst[e + k]);
                    if (d >= lo && d < hi) atomicAdd(&lh[d - lo], 1);
                }
            }
        }
        __syncthreads();
        int* out = ghist + (size_t)blockIdx.x * NPB;   // blockIdx = part + NPART*chunk... see chunksum idx
        for (int b = threadIdx.x; b < nb; b += 256) out[b] = lh[b];
    } else {
        int bi = blockIdx.x - NPART * NCHUNK;
        int tid = bi * 256 + threadIdx.x;
        int node = tid >> 4;
        int c8 = tid & 15;
        if (node >= nnodes) return;
        int tok = x[node];
        float4 f0 = ((const float4*)emb)[(size_t)tok * 32 + c8 * 2];
        float4 f1 = ((const float4*)emb)[(size_t)tok * 32 + c8 * 2 + 1];
        bf16x8 o;
        o[0] = f2bf(f0.x); o[1] = f2bf(f0.y); o[2] = f2bf(f0.z); o[3] = f2bf(f0.w);
        o[4] = f2bf(f1.x); o[5] = f2bf(f1.y); o[6] = f2bf(f1.z); o[7] = f2bf(f1.w);
        *(bf16x8*)(h + (size_t)node * HID + c8 * 8) = o;
    }
}

// ------- per-node chunk-exclusive prefix (in place) + total degree -------
// ghist slab index for (part,chunk) is blockIdx = part + 8*chunk (matches radix_embed_k).
__global__ __launch_bounds__(256) void chunksum_k(int* __restrict__ ghist,
                                                  int* __restrict__ degsum,
                                                  int nnodes, int NPB) {
    int node = blockIdx.x * 256 + threadIdx.x;
    if (node >= nnodes) return;
    int part = node / NPB;
    int bin = node - part * NPB;
    int running = 0;
    #pragma unroll 4
    for (int c = 0; c < NCHUNK; ++c) {
        size_t idx = (size_t)(part + NPART * c) * NPB + bin;
        int v = ghist[idx];
        ghist[idx] = running;
        running += v;
    }
    degsum[node] = running;
}

// ------- decoupled-lookback exclusive scan over degsum (blocks <= 64) -------
__global__ __launch_bounds__(1024) void scan_k(const int* __restrict__ deg,
                                               int* __restrict__ rowstart,
                                               int n, int* bsum, int* bflag, int nblocks) {
    __shared__ int wsum[16];
    __shared__ int prefix_s, total_s;
    const int b = blockIdx.x;
    const int t = threadIdx.x, lane = t & 63, w = t >> 6;
    const int i4 = b * 4096 + t * 4;
    int4 v = make_int4(0, 0, 0, 0);
    if (i4 + 3 < n) v = *(const int4*)(deg + i4);
    else if (i4 < n) {
        v.x = deg[i4];
        if (i4 + 1 < n) v.y = deg[i4 + 1];
        if (i4 + 2 < n) v.z = deg[i4 + 2];
    }
    int s1 = v.x + v.y, s2 = s1 + v.z, s3 = s2 + v.w;
    int sum = s3;
    #pragma unroll
    for (int off = 1; off < 64; off <<= 1) {
        int o = __shfl_up(sum, off, 64);
        if (lane >= off) sum += o;
    }
    if (lane == 63) wsum[w] = sum;
    __syncthreads();
    if (t == 0) {
        int run = 0;
        #pragma unroll
        for (int k = 0; k < 16; ++k) { int xx = wsum[k]; wsum[k] = run; run += xx; }
        total_s = run;
        atomicExch(&bsum[b], run);
        __threadfence();
        atomicExch(&bflag[b], 1);
    }
    __syncthreads();
    if (w == 0) {
        int p = 0;
        if (lane < b) {
            while (atomicAdd(&bflag[lane], 0) == 0) {}
            p = atomicAdd(&bsum[lane], 0);
        }
        #pragma unroll
        for (int off = 32; off >= 1; off >>= 1) p += __shfl_down(p, off, 64);
        if (lane == 0) prefix_s = p;
    }
    __syncthreads();
    const int excl = (sum - s3) + wsum[w] + prefix_s;
    if (i4 + 3 < n) {
        *(int4*)(rowstart + i4) = make_int4(excl, excl + v.x, excl + s1, excl + s2);
    } else if (i4 < n) {
        rowstart[i4] = excl;
        if (i4 + 1 < n) rowstart[i4 + 1] = excl + v.x;
        if (i4 + 2 < n) rowstart[i4 + 2] = excl + s1;
    }
    if (b == nblocks - 1 && t == 1023) rowstart[n] = prefix_s + total_s;
}

// ------- fill via LDS cursors: zero global atomics -------
__global__ __launch_bounds__(256) void fill2_k(const int* __restrict__ src,
                                               const int* __restrict__ dst,
                                               const int* __restrict__ rowstart,
                                               const int* __restrict__ ghist,
                                               int* __restrict__ sorted_src,
                                               int nedges, int nnodes, int NPB, int ECH) {
    __shared__ int cur[MAXBIN];
    const int part = blockIdx.x & (NPART - 1);
    const int chunk = blockIdx.x >> 3;
    const int lo = part * NPB;
    const int hi = min(lo + NPB, nnodes);
    const int nb = hi - lo;
    const int* base = ghist + (size_t)blockIdx.x * NPB;
    for (int b = threadIdx.x; b < nb; b += 256)
        cur[b] = rowstart[lo + b] + base[b];
    __syncthreads();
    const int e0 = chunk * ECH;
    const int e1 = min(nedges, e0 + ECH);
    for (int bb = e0; bb < e1; bb += 1024) {
        int e = bb + (threadIdx.x << 2);
        if (e + 4 <= e1) {
            int4v d4 = __builtin_nontemporal_load((const int4v*)(dst + e));
            #pragma unroll
            for (int k = 0; k < 4; ++k) {
                int d = d4[k];
                if (d >= lo && d < hi) {
                    int s = __builtin_nontemporal_load(&src[e + k]);
                    int pos = atomicAdd(&cur[d - lo], 1);   // LDS atomic
                    sorted_src[pos] = s;
                }
            }
        } else {
            for (int k = 0; k < 4 && e + k < e1; ++k) {
                int d = __builtin_nontemporal_load(&dst[e + k]);
                if (d >= lo && d < hi) {
                    int s = __builtin_nontemporal_load(&src[e + k]);
                    int pos = atomicAdd(&cur[d - lo], 1);
                    sorted_src[pos] = s;
                }
            }
        }
    }
}

// ---------------- gather-aggregate (bf16 h), 4-deep MLP ----------------
__global__ __launch_bounds__(256) void gather_k(const int* __restrict__ rowstart,
                                                const int* __restrict__ sorted_src,
                                                const short* __restrict__ h,
                                                short* __restrict__ agg, int nnodes) {
    int tid = blockIdx.x * 256 + threadIdx.x;
    int node = tid >> 4;
    int l = tid & 15;
    if (node >= nnodes) return;
    int beg = rowstart[node];
    int end = rowstart[node + 1];
    const bf16x8* hr = (const bf16x8*)h;
    float a[8];
    #pragma unroll
    for (int i = 0; i < 8; ++i) a[i] = 0.f;
    int e = beg;
    for (; e + 4 <= end; e += 4) {
        int s0 = sorted_src[e];
        int s1 = sorted_src[e + 1];
        int s2 = sorted_src[e + 2];
        int s3 = sorted_src[e + 3];
        bf16x8 v0 = hr[(size_t)s0 * 16 + l];
        bf16x8 v1 = hr[(size_t)s1 * 16 + l];
        bf16x8 v2 = hr[(size_t)s2 * 16 + l];
        bf16x8 v3 = hr[(size_t)s3 * 16 + l];
        #pragma unroll
        for (int i = 0; i < 8; ++i) a[i] += bf2f(v0[i]);
        #pragma unroll
        for (int i = 0; i < 8; ++i) a[i] += bf2f(v1[i]);
        #pragma unroll
        for (int i = 0; i < 8; ++i) a[i] += bf2f(v2[i]);
        #pragma unroll
        for (int i = 0; i < 8; ++i) a[i] += bf2f(v3[i]);
    }
    for (; e < end; ++e) {
        bf16x8 v0 = hr[(size_t)sorted_src[e] * 16 + l];
        #pragma unroll
        for (int i = 0; i < 8; ++i) a[i] += bf2f(v0[i]);
    }
    bf16x8 o;
    #pragma unroll
    for (int i = 0; i < 8; ++i) o[i] = f2bf(a[i]);
    *(bf16x8*)(agg + (size_t)node * HID + l * 8) = o;
}

// ---------------- weight pack: all three weight sets in one launch ----------------
__global__ __launch_bounds__(256) void pack_all_k(const float* __restrict__ Wih0,
                                                  const float* __restrict__ Whh0,
                                                  const float* __restrict__ Wih1,
                                                  const float* __restrict__ Whh1,
                                                  const float* __restrict__ dW,
                                                  short* __restrict__ P0,
                                                  short* __restrict__ P1,
                                                  short* __restrict__ Pd) {
    int b = blockIdx.x;
    const float* WA; const float* WB; short* P; int ntilesA; int tile;
    if (b < 48)      { WA = Wih0; WB = Whh0; P = P0; ntilesA = 24; tile = b; }
    else if (b < 96) { WA = Wih1; WB = Whh1; P = P1; ntilesA = 24; tile = b - 48; }
    else             { WA = dW;   WB = dW;   P = Pd; ntilesA = 8;  tile = b - 96; }
    const int t = threadIdx.x;
    const int lane = t & 63, k0 = t >> 6;
    const float* W;
    int row;
    if (tile < ntilesA) { W = WA; row = tile * 16 + (lane & 15); }
    else                { W = WB; row = (tile - ntilesA) * 16 + (lane & 15); }
    const int k = k0 * 32 + (lane >> 4) * 8;
    const float4 f0 = *(const float4*)(W + row * HID + k);
    const float4 f1 = *(const float4*)(W + row * HID + k + 4);
    short4 o0 = make_short4(f2bf(f0.x), f2bf(f0.y), f2bf(f0.z), f2bf(f0.w));
    short4 o1 = make_short4(f2bf(f1.x), f2bf(f1.y), f2bf(f1.z), f2bf(f1.w));
    short* dstp = P + ((size_t)(tile * 4 + k0) * 64 + lane) * 8;
    *(short4*)(dstp) = o0;
    *(short4*)(dstp + 4) = o1;
}

// ---------------- MFMA fused GRU cell, 16-row tile (bf16 in/out) ----------------
__global__ __launch_bounds__(256) void gru_mfma_k(const short* __restrict__ agg,
                                                  const short* __restrict__ hin,
                                                  short* __restrict__ hout,
                                                  const short* __restrict__ P,
                                                  const float* __restrict__ bih,
                                                  const float* __restrict__ bhh,
                                                  int nnodes) {
    __shared__ short As[16 * LDA];
    __shared__ short Hs[16 * LDA];
    const int t = threadIdx.x;
    const int mbase = blockIdx.x * 16;
    {
        int row = t >> 4, c8 = t & 15;
        int node = mbase + row;
        bf16x8 a = (bf16x8){0,0,0,0,0,0,0,0};
        bf16x8 hh = (bf16x8){0,0,0,0,0,0,0,0};
        if (node < nnodes) {
            a  = *(const bf16x8*)(agg + (size_t)node * HID + c8 * 8);
            hh = *(const bf16x8*)(hin + (size_t)node * HID + c8 * 8);
        }
        *(bf16x8*)&As[row * LDA + c8 * 8] = a;
        *(bf16x8*)&Hs[row * LDA + c8 * 8] = hh;
    }
    __syncthreads();

    const int w = t >> 6, lane = t & 63;
    const int ml = lane & 15, kq = lane >> 4;
    const int j0 = w * 32;

    f32x4 acc[12];  // idx = (mat*3 + gate)*2 + ctt
    #pragma unroll
    for (int i = 0; i < 12; ++i) acc[i] = (f32x4){0.f, 0.f, 0.f, 0.f};

    const short* Pb = P + (size_t)lane * 8;

    #pragma unroll
    for (int k0 = 0; k0 < 4; ++k0) {
        bf16x8 aa = *(const bf16x8*)&As[ml * LDA + k0 * 32 + kq * 8];
        bf16x8 ah = *(const bf16x8*)&Hs[ml * LDA + k0 * 32 + kq * 8];
        #pragma unroll
        for (int m = 0; m < 2; ++m) {
            #pragma unroll
            for (int g = 0; g < 3; ++g) {
                #pragma unroll
                for (int ctt = 0; ctt < 2; ++ctt) {
                    const int tile = m * 24 + g * 8 + (w << 1) + ctt;
                    bf16x8 bb = *(const bf16x8*)(Pb + (size_t)(tile * 4 + k0) * 512);
                    const int idx = (m * 3 + g) * 2 + ctt;
                    acc[idx] = __builtin_amdgcn_mfma_f32_16x16x32_bf16(
                        (m == 0) ? aa : ah, bb, acc[idx], 0, 0, 0);
                }
            }
        }
    }

    #pragma unroll
    for (int ctt = 0; ctt < 2; ++ctt) {
        const int col = j0 + ctt * 16 + ml;
        const float b_ir = bih[col], b_iz = bih[col + 128], b_in = bih[col + 256];
        const float b_hr = bhh[col], b_hz = bhh[col + 128], b_hn = bhh[col + 256];
        #pragma unroll
        for (int r = 0; r < 4; ++r) {
            const int row = kq * 4 + r;
            const int node = mbase + row;
            float ir = acc[0 + ctt][r] + b_ir;
            float iz = acc[2 + ctt][r] + b_iz;
            float in_ = acc[4 + ctt][r] + b_in;
            float hr = acc[6 + ctt][r] + b_hr;
            float hz = acc[8 + ctt][r] + b_hz;
            float hn = acc[10 + ctt][r] + b_hn;
            float rr = 1.f / (1.f + expf(-(ir + hr)));
            float z  = 1.f / (1.f + expf(-(iz + hz)));
            float n  = tanhf(in_ + rr * hn);
            if (node < nnodes) {
                float hval = bf2f(Hs[row * LDA + col]);
                hout[(size_t)node * HID + col] = f2bf((1.f - z) * n + z * hval);
            }
        }
    }
}

// ------- layer-1 GRU fused with dense (16-row tile): h' round-trips through LDS -------
__global__ __launch_bounds__(256) void gru_dense_k(const short* __restrict__ agg,
                                                   const short* __restrict__ hin,
                                                   short* __restrict__ yout,
                                                   const short* __restrict__ P,
                                                   const float* __restrict__ bih,
                                                   const float* __restrict__ bhh,
                                                   const short* __restrict__ Pd,
                                                   const float* __restrict__ db,
                                                   int nnodes) {
    __shared__ short As[16 * LDA];
    __shared__ short Hs[16 * LDA];
    const int t = threadIdx.x;
    const int mbase = blockIdx.x * 16;
    {
        int row = t >> 4, c8 = t & 15;
        int node = mbase + row;
        bf16x8 a = (bf16x8){0,0,0,0,0,0,0,0};
        bf16x8 hh = (bf16x8){0,0,0,0,0,0,0,0};
        if (node < nnodes) {
            a  = *(const bf16x8*)(agg + (size_t)node * HID + c8 * 8);
            hh = *(const bf16x8*)(hin + (size_t)node * HID + c8 * 8);
        }
        *(bf16x8*)&As[row * LDA + c8 * 8] = a;
        *(bf16x8*)&Hs[row * LDA + c8 * 8] = hh;
    }
    __syncthreads();

    const int w = t >> 6, lane = t & 63;
    const int ml = lane & 15, kq = lane >> 4;
    const int j0 = w * 32;

    f32x4 acc[12];
    #pragma unroll
    for (int i = 0; i < 12; ++i) acc[i] = (f32x4){0.f, 0.f, 0.f, 0.f};

    const short* Pb = P + (size_t)lane * 8;

    #pragma unroll
    for (int k0 = 0; k0 < 4; ++k0) {
        bf16x8 aa = *(const bf16x8*)&As[ml * LDA + k0 * 32 + kq * 8];
        bf16x8 ah = *(const bf16x8*)&Hs[ml * LDA + k0 * 32 + kq * 8];
        #pragma unroll
        for (int m = 0; m < 2; ++m) {
            #pragma unroll
            for (int g = 0; g < 3; ++g) {
                #pragma unroll
                for (int ctt = 0; ctt < 2; ++ctt) {
                    const int tile = m * 24 + g * 8 + (w << 1) + ctt;
                    bf16x8 bb = *(const bf16x8*)(Pb + (size_t)(tile * 4 + k0) * 512);
                    const int idx = (m * 3 + g) * 2 + ctt;
                    acc[idx] = __builtin_amdgcn_mfma_f32_16x16x32_bf16(
                        (m == 0) ? aa : ah, bb, acc[idx], 0, 0, 0);
                }
            }
        }
    }

    // GRU epilogue -> h' in registers
    short hnew[2][4];
    #pragma unroll
    for (int ctt = 0; ctt < 2; ++ctt) {
        const int col = j0 + ctt * 16 + ml;
        const float b_ir = bih[col], b_iz = bih[col + 128], b_in = bih[col + 256];
        const float b_hr = bhh[col], b_hz = bhh[col + 128], b_hn = bhh[col + 256];
        #pragma unroll
        for (int r = 0; r < 4; ++r) {
            const int row = kq * 4 + r;
            float ir = acc[0 + ctt][r] + b_ir;
            float iz = acc[2 + ctt][r] + b_iz;
            float in_ = acc[4 + ctt][r] + b_in;
            float hr = acc[6 + ctt][r] + b_hr;
            float hz = acc[8 + ctt][r] + b_hz;
            float hn = acc[10 + ctt][r] + b_hn;
            float rr = 1.f / (1.f + expf(-(ir + hr)));
            float z  = 1.f / (1.f + expf(-(iz + hz)));
            float n  = tanhf(in_ + rr * hn);
            float hval = bf2f(Hs[row * LDA + col]);
            hnew[ctt][r] = f2bf((1.f - z) * n + z * hval);
        }
    }

    __syncthreads();   // all waves finished reading As/Hs
    #pragma unroll
    for (int ctt = 0; ctt < 2; ++ctt) {
        const int col = j0 + ctt * 16 + ml;
        #pragma unroll
        for (int r = 0; r < 4; ++r)
            As[(kq * 4 + r) * LDA + col] = hnew[ctt][r];
    }
    __syncthreads();

    // dense phase: y = h' @ dW.T + db
    f32x4 dacc[2];
    dacc[0] = (f32x4){0.f, 0.f, 0.f, 0.f};
    dacc[1] = (f32x4){0.f, 0.f, 0.f, 0.f};
    const short* Pbd = Pd + (size_t)lane * 8;
    #pragma unroll
    for (int k0 = 0; k0 < 4; ++k0) {
        bf16x8 aa = *(const bf16x8*)&As[ml * LDA + k0 * 32 + kq * 8];
        #pragma unroll
        for (int ctt = 0; ctt < 2; ++ctt) {
            const int tile = (w << 1) + ctt;
            bf16x8 bb = *(const bf16x8*)(Pbd + (size_t)(tile * 4 + k0) * 512);
            dacc[ctt] = __builtin_amdgcn_mfma_f32_16x16x32_bf16(aa, bb, dacc[ctt], 0, 0, 0);
        }
    }
    #pragma unroll
    for (int ctt = 0; ctt < 2; ++ctt) {
        const int col = j0 + ctt * 16 + ml;
        const float bias = db[col];
        #pragma unroll
        for (int r = 0; r < 4; ++r) {
            const int node = mbase + kq * 4 + r;
            if (node < nnodes)
                yout[(size_t)node * HID + col] = f2bf(dacc[ctt][r] + bias);
        }
    }
}

// ---------------- segment max pool, 4-way split per graph ----------------
__global__ __launch_bounds__(256) void pool_k(const short* __restrict__ xh,
                                              const int* __restrict__ batch,
                                              int nnodes, float* __restrict__ pmax) {
    const int g = blockIdx.x >> 2;
    const int p = blockIdx.x & (POOL_P - 1);
    int lo = 0, hi = nnodes;
    while (lo < hi) { int mid = (lo + hi) >> 1; if (batch[mid] < g) lo = mid + 1; else hi = mid; }
    int start = lo;
    lo = 0; hi = nnodes;
    while (lo < hi) { int mid = (lo + hi) >> 1; if (batch[mid] < g + 1) lo = mid + 1; else hi = mid; }
    int end = lo;
    int len = end - start;
    int q0 = start + (int)(((long long)len * p) / POOL_P);
    int q1 = start + (int)(((long long)len * (p + 1)) / POOL_P);

    const int rg = threadIdx.x >> 6;
    const int j2 = threadIdx.x & 63;
    float m0 = -INFINITY, m1 = -INFINITY;
    for (int i = q0 + rg; i < q1; i += 4) {
        unsigned int u = *(const unsigned int*)(xh + (size_t)i * HID + j2 * 2);
        m0 = fmaxf(m0, __uint_as_float(u << 16));
        m1 = fmaxf(m1, __uint_as_float(u & 0xFFFF0000u));
    }
    __shared__ float pm[4][130];
    pm[rg][j2 * 2] = m0;
    pm[rg][j2 * 2 + 1] = m1;
    __syncthreads();
    if (rg == 0) {
        float a = fmaxf(fmaxf(pm[0][j2 * 2], pm[1][j2 * 2]), fmaxf(pm[2][j2 * 2], pm[3][j2 * 2]));
        float c = fmaxf(fmaxf(pm[0][j2 * 2 + 1], pm[1][j2 * 2 + 1]), fmaxf(pm[2][j2 * 2 + 1], pm[3][j2 * 2 + 1]));
        *(float2*)(pmax + (size_t)blockIdx.x * HID + j2 * 2) = make_float2(a, c);
    }
}

// ---------------- classifier ----------------
__global__ __launch_bounds__(128) void clf_k(const float* __restrict__ pmax,
                                             const float* __restrict__ W,
                                             const float* __restrict__ b,
                                             float* __restrict__ out) {
    __shared__ float red[2];
    const int g = blockIdx.x;
    const int t = threadIdx.x;
    float m = -INFINITY;
    #pragma unroll
    for (int p = 0; p < POOL_P; ++p)
        m = fmaxf(m, pmax[((size_t)g * POOL_P + p) * HID + t]);
    float v = m * W[t];
    #pragma unroll
    for (int off = 32; off >= 1; off >>= 1) v += __shfl_down(v, off, 64);
    if ((t & 63) == 0) red[t >> 6] = v;
    __syncthreads();
    if (t == 0) {
        float s = red[0] + red[1] + b[0];
        out[g] = 1.f / (1.f + expf(-s));
    }
}

extern "C" void kernel_launch(void* const* d_in, const int* in_sizes, int n_in,
                              void* d_out, int out_size, void* d_ws, size_t ws_size,
                              hipStream_t stream) {
    const int* x      = (const int*)d_in[0];
    const int* ei     = (const int*)d_in[1];
    const int* batch  = (const int*)d_in[2];
    const float* emb  = (const float*)d_in[3];
    const float* Wih0 = (const float*)d_in[4];
    const float* Whh0 = (const float*)d_in[5];
    const float* bih0 = (const float*)d_in[6];
    const float* bhh0 = (const float*)d_in[7];
    const float* Wih1 = (const float*)d_in[8];
    const float* Whh1 = (const float*)d_in[9];
    const float* bih1 = (const float*)d_in[10];
    const float* bhh1 = (const float*)d_in[11];
    const float* dW   = (const float*)d_in[12];
    const float* db   = (const float*)d_in[13];
    const float* cW   = (const float*)d_in[14];
    const float* cb   = (const float*)d_in[15];

    const int N = in_sizes[0];          // 100000
    const int E = in_sizes[1] / 2;      // 1600000
    const int NG = out_size;            // 128
    const size_t NH = (size_t)N * HID;
    const int NPB = (N + NPART - 1) / NPART;          // bins/partition (12500 <= MAXBIN)
    const int ECH = (E + NCHUNK - 1) / NCHUNK;        // edges/chunk

    short* hb0 = (short*)d_ws;                        // NH bf16
    short* hb1 = hb0 + NH;                            // NH bf16 (agg)
    short* hb2 = hb1 + NH;                            // NH bf16
    short* P0  = hb2 + NH;
    short* P1  = P0 + 48 * 4 * 64 * 8;
    short* Pd  = P1 + 48 * 4 * 64 * 8;
    float* pmax = (float*)(Pd + 8 * 4 * 64 * 8);      // NG*POOL_P*HID
    int* bflag      = (int*)(pmax + (size_t)NG * POOL_P * HID);  // 64
    int* bsum       = bflag + 64;                     // 64
    int* degsum     = bsum + 64;                      // N
    int* rowstart   = degsum + N;                     // N+4
    int* ghist      = rowstart + (N + 4);             // NPART*NCHUNK*NPB
    int* sorted_src = ghist + (size_t)NPART * NCHUNK * NPB;  // E

    const int* esrc = ei;
    const int* edst = ei + E;

    dim3 blk(256);
    int embGrid  = (N * 16 + 255) / 256;
    int tileGrid = (N + 15) / 16;
    const int scanBlocks = (N + 4095) / 4096;   // 25 <= 64

    // weight packing
    pack_all_k<<<104, blk, 0, stream>>>(Wih0, Whh0, Wih1, Whh1, dW, P0, P1, Pd);

    // embed + LDS radix histogram (zero global atomics)
    hipMemsetAsync(bflag, 0, 64 * sizeof(int), stream);
    radix_embed_k<<<NPART * NCHUNK + embGrid, blk, 0, stream>>>(x, emb, hb0, N,
                                                                edst, ghist, E, NPB, ECH);

    // per-node chunk bases + degree, then lookback scan, then LDS-cursor fill
    chunksum_k<<<(N + 255) / 256, blk, 0, stream>>>(ghist, degsum, N, NPB);
    scan_k<<<scanBlocks, dim3(1024), 0, stream>>>(degsum, rowstart, N, bsum, bflag, scanBlocks);
    fill2_k<<<NPART * NCHUNK, blk, 0, stream>>>(esrc, edst, rowstart, ghist, sorted_src,
                                                E, N, NPB, ECH);

    // layer 0
    gather_k<<<embGrid, blk, 0, stream>>>(rowstart, sorted_src, hb0, hb1, N);
    gru_mfma_k<<<tileGrid, blk, 0, stream>>>(hb1, hb0, hb2, P0, bih0, bhh0, N);

    // layer 1 (+ dense fused)
    gather_k<<<embGrid, blk, 0, stream>>>(rowstart, sorted_src, hb2, hb1, N);
    gru_dense_k<<<tileGrid, blk, 0, stream>>>(hb1, hb2, hb0, P1, bih1, bhh1, Pd, db, N);

    // pool + classifier
    pool_k<<<NG * POOL_P, blk, 0, stream>>>(hb0, batch, N, pmax);
    clf_k<<<NG, dim3(128), 0, stream>>>(pmax, cW, cb, (float*)d_out);
}

// Round 9
// 452.218 us; speedup vs baseline: 1.2735x; 1.2532x over previous
//
#include <hip/hip_runtime.h>
#include <hip/hip_bf16.h>
#include <math.h>

#define HID 128
#define LDA 136   // bf16 LDS row stride (shorts)
#define POOL_P 4
#define NPART 8
#define NCHUNK 32
#define MAXBIN 12544   // LDS bins per partition (>= ceil(N/8)); 50.2 KB

typedef __attribute__((ext_vector_type(8))) short bf16x8;
typedef __attribute__((ext_vector_type(4))) float f32x4;
typedef __attribute__((ext_vector_type(4))) int int4v;

__device__ __forceinline__ short f2bf(float f) {
    unsigned int u = __float_as_uint(f);
    u += 0x7FFF + ((u >> 16) & 1);   // RNE
    return (short)(u >> 16);
}
__device__ __forceinline__ float bf2f(short s) {
    return __uint_as_float(((unsigned int)(unsigned short)s) << 16);
}

// ------- fused (1024 thr): blocks [0,256) per-(part,chunk) LDS histograms; rest embed -------
// Edge streams use CACHED loads: edge list (12.8 MB) is L3-resident, so the
// 8x per-partition re-read is served by Infinity Cache, not HBM (r8 lesson:
// nt loads forced 61 MB of HBM re-fetch).
__global__ __launch_bounds__(1024) void radix_embed_k(const int* __restrict__ x,
                                                      const float* __restrict__ emb,
                                                      short* __restrict__ h, int nnodes,
                                                      const int* __restrict__ dst,
                                                      int* __restrict__ ghist,
                                                      int nedges, int NPB, int ECH) {
    __shared__ int lh[MAXBIN];
    const int t = threadIdx.x;
    if ((int)blockIdx.x < NPART * NCHUNK) {
        const int part = blockIdx.x & (NPART - 1);
        const int chunk = blockIdx.x >> 3;          // /NPART
        const int lo = part * NPB;
        const int hi = min(lo + NPB, nnodes);
        const int nb = hi - lo;
        for (int b = t; b < nb; b += 1024) lh[b] = 0;
        __syncthreads();
        const int e0 = chunk * ECH;
        const int e1 = min(nedges, e0 + ECH);
        for (int base = e0; base < e1; base += 4096) {
            int e = base + (t << 2);
            if (e + 4 <= e1) {
                int4v d4 = *(const int4v*)(dst + e);
                #pragma unroll
                for (int k = 0; k < 4; ++k) {
                    int d = d4[k];
                    if (d >= lo && d < hi) atomicAdd(&lh[d - lo], 1);
                }
            } else {
                for (int k = 0; k < 4 && e + k < e1; ++k) {
                    int d = dst[e + k];
                    if (d >= lo && d < hi) atomicAdd(&lh[d - lo], 1);
                }
            }
        }
        __syncthreads();
        int* out = ghist + (size_t)blockIdx.x * NPB;
        for (int b = t; b < nb; b += 1024) out[b] = lh[b];
    } else {
        int bi = blockIdx.x - NPART * NCHUNK;
        int tid = bi * 1024 + t;
        int node = tid >> 4;
        int c8 = tid & 15;
        if (node >= nnodes) return;
        int tok = x[node];
        float4 f0 = ((const float4*)emb)[(size_t)tok * 32 + c8 * 2];
        float4 f1 = ((const float4*)emb)[(size_t)tok * 32 + c8 * 2 + 1];
        bf16x8 o;
        o[0] = f2bf(f0.x); o[1] = f2bf(f0.y); o[2] = f2bf(f0.z); o[3] = f2bf(f0.w);
        o[4] = f2bf(f1.x); o[5] = f2bf(f1.y); o[6] = f2bf(f1.z); o[7] = f2bf(f1.w);
        *(bf16x8*)(h + (size_t)node * HID + c8 * 8) = o;
    }
}

// ------- per-node chunk-exclusive prefix (in place) + total degree -------
__global__ __launch_bounds__(256) void chunksum_k(int* __restrict__ ghist,
                                                  int* __restrict__ degsum,
                                                  int nnodes, int NPB) {
    int node = blockIdx.x * 256 + threadIdx.x;
    if (node >= nnodes) return;
    int part = node / NPB;
    int bin = node - part * NPB;
    int running = 0;
    #pragma unroll 4
    for (int c = 0; c < NCHUNK; ++c) {
        size_t idx = (size_t)(part + NPART * c) * NPB + bin;
        int v = ghist[idx];
        ghist[idx] = running;
        running += v;
    }
    degsum[node] = running;
}

// ------- decoupled-lookback exclusive scan over degsum (blocks <= 64) -------
__global__ __launch_bounds__(1024) void scan_k(const int* __restrict__ deg,
                                               int* __restrict__ rowstart,
                                               int n, int* bsum, int* bflag, int nblocks) {
    __shared__ int wsum[16];
    __shared__ int prefix_s, total_s;
    const int b = blockIdx.x;
    const int t = threadIdx.x, lane = t & 63, w = t >> 6;
    const int i4 = b * 4096 + t * 4;
    int4 v = make_int4(0, 0, 0, 0);
    if (i4 + 3 < n) v = *(const int4*)(deg + i4);
    else if (i4 < n) {
        v.x = deg[i4];
        if (i4 + 1 < n) v.y = deg[i4 + 1];
        if (i4 + 2 < n) v.z = deg[i4 + 2];
    }
    int s1 = v.x + v.y, s2 = s1 + v.z, s3 = s2 + v.w;
    int sum = s3;
    #pragma unroll
    for (int off = 1; off < 64; off <<= 1) {
        int o = __shfl_up(sum, off, 64);
        if (lane >= off) sum += o;
    }
    if (lane == 63) wsum[w] = sum;
    __syncthreads();
    if (t == 0) {
        int run = 0;
        #pragma unroll
        for (int k = 0; k < 16; ++k) { int xx = wsum[k]; wsum[k] = run; run += xx; }
        total_s = run;
        atomicExch(&bsum[b], run);
        __threadfence();
        atomicExch(&bflag[b], 1);
    }
    __syncthreads();
    if (w == 0) {
        int p = 0;
        if (lane < b) {
            while (atomicAdd(&bflag[lane], 0) == 0) {}
            p = atomicAdd(&bsum[lane], 0);
        }
        #pragma unroll
        for (int off = 32; off >= 1; off >>= 1) p += __shfl_down(p, off, 64);
        if (lane == 0) prefix_s = p;
    }
    __syncthreads();
    const int excl = (sum - s3) + wsum[w] + prefix_s;
    if (i4 + 3 < n) {
        *(int4*)(rowstart + i4) = make_int4(excl, excl + v.x, excl + s1, excl + s2);
    } else if (i4 < n) {
        rowstart[i4] = excl;
        if (i4 + 1 < n) rowstart[i4 + 1] = excl + v.x;
        if (i4 + 2 < n) rowstart[i4 + 2] = excl + s1;
    }
    if (b == nblocks - 1 && t == 1023) rowstart[n] = prefix_s + total_s;
}

// ------- fill via LDS cursors (1024 thr): zero global atomics, cached edge reads -------
__global__ __launch_bounds__(1024) void fill2_k(const int* __restrict__ src,
                                                const int* __restrict__ dst,
                                                const int* __restrict__ rowstart,
                                                const int* __restrict__ ghist,
                                                int* __restrict__ sorted_src,
                                                int nedges, int nnodes, int NPB, int ECH) {
    __shared__ int cur[MAXBIN];
    const int t = threadIdx.x;
    const int part = blockIdx.x & (NPART - 1);
    const int chunk = blockIdx.x >> 3;
    const int lo = part * NPB;
    const int hi = min(lo + NPB, nnodes);
    const int nb = hi - lo;
    const int* base = ghist + (size_t)blockIdx.x * NPB;
    for (int b = t; b < nb; b += 1024)
        cur[b] = rowstart[lo + b] + base[b];
    __syncthreads();
    const int e0 = chunk * ECH;
    const int e1 = min(nedges, e0 + ECH);
    for (int bb = e0; bb < e1; bb += 4096) {
        int e = bb + (t << 2);
        if (e + 4 <= e1) {
            int4v d4 = *(const int4v*)(dst + e);
            #pragma unroll
            for (int k = 0; k < 4; ++k) {
                int d = d4[k];
                if (d >= lo && d < hi) {
                    int s = src[e + k];
                    int pos = atomicAdd(&cur[d - lo], 1);   // LDS atomic
                    sorted_src[pos] = s;
                }
            }
        } else {
            for (int k = 0; k < 4 && e + k < e1; ++k) {
                int d = dst[e + k];
                if (d >= lo && d < hi) {
                    int s = src[e + k];
                    int pos = atomicAdd(&cur[d - lo], 1);
                    sorted_src[pos] = s;
                }
            }
        }
    }
}

// ---------------- gather-aggregate (bf16 h), 4-deep MLP ----------------
__global__ __launch_bounds__(256) void gather_k(const int* __restrict__ rowstart,
                                                const int* __restrict__ sorted_src,
                                                const short* __restrict__ h,
                                                short* __restrict__ agg, int nnodes) {
    int tid = blockIdx.x * 256 + threadIdx.x;
    int node = tid >> 4;
    int l = tid & 15;
    if (node >= nnodes) return;
    int beg = rowstart[node];
    int end = rowstart[node + 1];
    const bf16x8* hr = (const bf16x8*)h;
    float a[8];
    #pragma unroll
    for (int i = 0; i < 8; ++i) a[i] = 0.f;
    int e = beg;
    for (; e + 4 <= end; e += 4) {
        int s0 = sorted_src[e];
        int s1 = sorted_src[e + 1];
        int s2 = sorted_src[e + 2];
        int s3 = sorted_src[e + 3];
        bf16x8 v0 = hr[(size_t)s0 * 16 + l];
        bf16x8 v1 = hr[(size_t)s1 * 16 + l];
        bf16x8 v2 = hr[(size_t)s2 * 16 + l];
        bf16x8 v3 = hr[(size_t)s3 * 16 + l];
        #pragma unroll
        for (int i = 0; i < 8; ++i) a[i] += bf2f(v0[i]);
        #pragma unroll
        for (int i = 0; i < 8; ++i) a[i] += bf2f(v1[i]);
        #pragma unroll
        for (int i = 0; i < 8; ++i) a[i] += bf2f(v2[i]);
        #pragma unroll
        for (int i = 0; i < 8; ++i) a[i] += bf2f(v3[i]);
    }
    for (; e < end; ++e) {
        bf16x8 v0 = hr[(size_t)sorted_src[e] * 16 + l];
        #pragma unroll
        for (int i = 0; i < 8; ++i) a[i] += bf2f(v0[i]);
    }
    bf16x8 o;
    #pragma unroll
    for (int i = 0; i < 8; ++i) o[i] = f2bf(a[i]);
    *(bf16x8*)(agg + (size_t)node * HID + l * 8) = o;
}

// ---------------- weight pack: all three weight sets in one launch ----------------
__global__ __launch_bounds__(256) void pack_all_k(const float* __restrict__ Wih0,
                                                  const float* __restrict__ Whh0,
                                                  const float* __restrict__ Wih1,
                                                  const float* __restrict__ Whh1,
                                                  const float* __restrict__ dW,
                                                  short* __restrict__ P0,
                                                  short* __restrict__ P1,
                                                  short* __restrict__ Pd) {
    int b = blockIdx.x;
    const float* WA; const float* WB; short* P; int ntilesA; int tile;
    if (b < 48)      { WA = Wih0; WB = Whh0; P = P0; ntilesA = 24; tile = b; }
    else if (b < 96) { WA = Wih1; WB = Whh1; P = P1; ntilesA = 24; tile = b - 48; }
    else             { WA = dW;   WB = dW;   P = Pd; ntilesA = 8;  tile = b - 96; }
    const int t = threadIdx.x;
    const int lane = t & 63, k0 = t >> 6;
    const float* W;
    int row;
    if (tile < ntilesA) { W = WA; row = tile * 16 + (lane & 15); }
    else                { W = WB; row = (tile - ntilesA) * 16 + (lane & 15); }
    const int k = k0 * 32 + (lane >> 4) * 8;
    const float4 f0 = *(const float4*)(W + row * HID + k);
    const float4 f1 = *(const float4*)(W + row * HID + k + 4);
    short4 o0 = make_short4(f2bf(f0.x), f2bf(f0.y), f2bf(f0.z), f2bf(f0.w));
    short4 o1 = make_short4(f2bf(f1.x), f2bf(f1.y), f2bf(f1.z), f2bf(f1.w));
    short* dstp = P + ((size_t)(tile * 4 + k0) * 64 + lane) * 8;
    *(short4*)(dstp) = o0;
    *(short4*)(dstp + 4) = o1;
}

// ---------------- MFMA fused GRU cell, 16-row tile (bf16 in/out) ----------------
__global__ __launch_bounds__(256) void gru_mfma_k(const short* __restrict__ agg,
                                                  const short* __restrict__ hin,
                                                  short* __restrict__ hout,
                                                  const short* __restrict__ P,
                                                  const float* __restrict__ bih,
                                                  const float* __restrict__ bhh,
                                                  int nnodes) {
    __shared__ short As[16 * LDA];
    __shared__ short Hs[16 * LDA];
    const int t = threadIdx.x;
    const int mbase = blockIdx.x * 16;
    {
        int row = t >> 4, c8 = t & 15;
        int node = mbase + row;
        bf16x8 a = (bf16x8){0,0,0,0,0,0,0,0};
        bf16x8 hh = (bf16x8){0,0,0,0,0,0,0,0};
        if (node < nnodes) {
            a  = *(const bf16x8*)(agg + (size_t)node * HID + c8 * 8);
            hh = *(const bf16x8*)(hin + (size_t)node * HID + c8 * 8);
        }
        *(bf16x8*)&As[row * LDA + c8 * 8] = a;
        *(bf16x8*)&Hs[row * LDA + c8 * 8] = hh;
    }
    __syncthreads();

    const int w = t >> 6, lane = t & 63;
    const int ml = lane & 15, kq = lane >> 4;
    const int j0 = w * 32;

    f32x4 acc[12];  // idx = (mat*3 + gate)*2 + ctt
    #pragma unroll
    for (int i = 0; i < 12; ++i) acc[i] = (f32x4){0.f, 0.f, 0.f, 0.f};

    const short* Pb = P + (size_t)lane * 8;

    #pragma unroll
    for (int k0 = 0; k0 < 4; ++k0) {
        bf16x8 aa = *(const bf16x8*)&As[ml * LDA + k0 * 32 + kq * 8];
        bf16x8 ah = *(const bf16x8*)&Hs[ml * LDA + k0 * 32 + kq * 8];
        #pragma unroll
        for (int m = 0; m < 2; ++m) {
            #pragma unroll
            for (int g = 0; g < 3; ++g) {
                #pragma unroll
                for (int ctt = 0; ctt < 2; ++ctt) {
                    const int tile = m * 24 + g * 8 + (w << 1) + ctt;
                    bf16x8 bb = *(const bf16x8*)(Pb + (size_t)(tile * 4 + k0) * 512);
                    const int idx = (m * 3 + g) * 2 + ctt;
                    acc[idx] = __builtin_amdgcn_mfma_f32_16x16x32_bf16(
                        (m == 0) ? aa : ah, bb, acc[idx], 0, 0, 0);
                }
            }
        }
    }

    #pragma unroll
    for (int ctt = 0; ctt < 2; ++ctt) {
        const int col = j0 + ctt * 16 + ml;
        const float b_ir = bih[col], b_iz = bih[col + 128], b_in = bih[col + 256];
        const float b_hr = bhh[col], b_hz = bhh[col + 128], b_hn = bhh[col + 256];
        #pragma unroll
        for (int r = 0; r < 4; ++r) {
            const int row = kq * 4 + r;
            const int node = mbase + row;
            float ir = acc[0 + ctt][r] + b_ir;
            float iz = acc[2 + ctt][r] + b_iz;
            float in_ = acc[4 + ctt][r] + b_in;
            float hr = acc[6 + ctt][r] + b_hr;
            float hz = acc[8 + ctt][r] + b_hz;
            float hn = acc[10 + ctt][r] + b_hn;
            float rr = 1.f / (1.f + expf(-(ir + hr)));
            float z  = 1.f / (1.f + expf(-(iz + hz)));
            float n  = tanhf(in_ + rr * hn);
            if (node < nnodes) {
                float hval = bf2f(Hs[row * LDA + col]);
                hout[(size_t)node * HID + col] = f2bf((1.f - z) * n + z * hval);
            }
        }
    }
}

// ------- layer-1 GRU fused with dense (16-row tile): h' round-trips through LDS -------
__global__ __launch_bounds__(256) void gru_dense_k(const short* __restrict__ agg,
                                                   const short* __restrict__ hin,
                                                   short* __restrict__ yout,
                                                   const short* __restrict__ P,
                                                   const float* __restrict__ bih,
                                                   const float* __restrict__ bhh,
                                                   const short* __restrict__ Pd,
                                                   const float* __restrict__ db,
                                                   int nnodes) {
    __shared__ short As[16 * LDA];
    __shared__ short Hs[16 * LDA];
    const int t = threadIdx.x;
    const int mbase = blockIdx.x * 16;
    {
        int row = t >> 4, c8 = t & 15;
        int node = mbase + row;
        bf16x8 a = (bf16x8){0,0,0,0,0,0,0,0};
        bf16x8 hh = (bf16x8){0,0,0,0,0,0,0,0};
        if (node < nnodes) {
            a  = *(const bf16x8*)(agg + (size_t)node * HID + c8 * 8);
            hh = *(const bf16x8*)(hin + (size_t)node * HID + c8 * 8);
        }
        *(bf16x8*)&As[row * LDA + c8 * 8] = a;
        *(bf16x8*)&Hs[row * LDA + c8 * 8] = hh;
    }
    __syncthreads();

    const int w = t >> 6, lane = t & 63;
    const int ml = lane & 15, kq = lane >> 4;
    const int j0 = w * 32;

    f32x4 acc[12];
    #pragma unroll
    for (int i = 0; i < 12; ++i) acc[i] = (f32x4){0.f, 0.f, 0.f, 0.f};

    const short* Pb = P + (size_t)lane * 8;

    #pragma unroll
    for (int k0 = 0; k0 < 4; ++k0) {
        bf16x8 aa = *(const bf16x8*)&As[ml * LDA + k0 * 32 + kq * 8];
        bf16x8 ah = *(const bf16x8*)&Hs[ml * LDA + k0 * 32 + kq * 8];
        #pragma unroll
        for (int m = 0; m < 2; ++m) {
            #pragma unroll
            for (int g = 0; g < 3; ++g) {
                #pragma unroll
                for (int ctt = 0; ctt < 2; ++ctt) {
                    const int tile = m * 24 + g * 8 + (w << 1) + ctt;
                    bf16x8 bb = *(const bf16x8*)(Pb + (size_t)(tile * 4 + k0) * 512);
                    const int idx = (m * 3 + g) * 2 + ctt;
                    acc[idx] = __builtin_amdgcn_mfma_f32_16x16x32_bf16(
                        (m == 0) ? aa : ah, bb, acc[idx], 0, 0, 0);
                }
            }
        }
    }

    // GRU epilogue -> h' in registers
    short hnew[2][4];
    #pragma unroll
    for (int ctt = 0; ctt < 2; ++ctt) {
        const int col = j0 + ctt * 16 + ml;
        const float b_ir = bih[col], b_iz = bih[col + 128], b_in = bih[col + 256];
        const float b_hr = bhh[col], b_hz = bhh[col + 128], b_hn = bhh[col + 256];
        #pragma unroll
        for (int r = 0; r < 4; ++r) {
            const int row = kq * 4 + r;
            float ir = acc[0 + ctt][r] + b_ir;
            float iz = acc[2 + ctt][r] + b_iz;
            float in_ = acc[4 + ctt][r] + b_in;
            float hr = acc[6 + ctt][r] + b_hr;
            float hz = acc[8 + ctt][r] + b_hz;
            float hn = acc[10 + ctt][r] + b_hn;
            float rr = 1.f / (1.f + expf(-(ir + hr)));
            float z  = 1.f / (1.f + expf(-(iz + hz)));
            float n  = tanhf(in_ + rr * hn);
            float hval = bf2f(Hs[row * LDA + col]);
            hnew[ctt][r] = f2bf((1.f - z) * n + z * hval);
        }
    }

    __syncthreads();   // all waves finished reading As/Hs
    #pragma unroll
    for (int ctt = 0; ctt < 2; ++ctt) {
        const int col = j0 + ctt * 16 + ml;
        #pragma unroll
        for (int r = 0; r < 4; ++r)
            As[(kq * 4 + r) * LDA + col] = hnew[ctt][r];
    }
    __syncthreads();

    // dense phase: y = h' @ dW.T + db
    f32x4 dacc[2];
    dacc[0] = (f32x4){0.f, 0.f, 0.f, 0.f};
    dacc[1] = (f32x4){0.f, 0.f, 0.f, 0.f};
    const short* Pbd = Pd + (size_t)lane * 8;
    #pragma unroll
    for (int k0 = 0; k0 < 4; ++k0) {
        bf16x8 aa = *(const bf16x8*)&As[ml * LDA + k0 * 32 + kq * 8];
        #pragma unroll
        for (int ctt = 0; ctt < 2; ++ctt) {
            const int tile = (w << 1) + ctt;
            bf16x8 bb = *(const bf16x8*)(Pbd + (size_t)(tile * 4 + k0) * 512);
            dacc[ctt] = __builtin_amdgcn_mfma_f32_16x16x32_bf16(aa, bb, dacc[ctt], 0, 0, 0);
        }
    }
    #pragma unroll
    for (int ctt = 0; ctt < 2; ++ctt) {
        const int col = j0 + ctt * 16 + ml;
        const float bias = db[col];
        #pragma unroll
        for (int r = 0; r < 4; ++r) {
            const int node = mbase + kq * 4 + r;
            if (node < nnodes)
                yout[(size_t)node * HID + col] = f2bf(dacc[ctt][r] + bias);
        }
    }
}

// ---------------- segment max pool, 4-way split per graph ----------------
__global__ __launch_bounds__(256) void pool_k(const short* __restrict__ xh,
                                              const int* __restrict__ batch,
                                              int nnodes, float* __restrict__ pmax) {
    const int g = blockIdx.x >> 2;
    const int p = blockIdx.x & (POOL_P - 1);
    int lo = 0, hi = nnodes;
    while (lo < hi) { int mid = (lo + hi) >> 1; if (batch[mid] < g) lo = mid + 1; else hi = mid; }
    int start = lo;
    lo = 0; hi = nnodes;
    while (lo < hi) { int mid = (lo + hi) >> 1; if (batch[mid] < g + 1) lo = mid + 1; else hi = mid; }
    int end = lo;
    int len = end - start;
    int q0 = start + (int)(((long long)len * p) / POOL_P);
    int q1 = start + (int)(((long long)len * (p + 1)) / POOL_P);

    const int rg = threadIdx.x >> 6;
    const int j2 = threadIdx.x & 63;
    float m0 = -INFINITY, m1 = -INFINITY;
    for (int i = q0 + rg; i < q1; i += 4) {
        unsigned int u = *(const unsigned int*)(xh + (size_t)i * HID + j2 * 2);
        m0 = fmaxf(m0, __uint_as_float(u << 16));
        m1 = fmaxf(m1, __uint_as_float(u & 0xFFFF0000u));
    }
    __shared__ float pm[4][130];
    pm[rg][j2 * 2] = m0;
    pm[rg][j2 * 2 + 1] = m1;
    __syncthreads();
    if (rg == 0) {
        float a = fmaxf(fmaxf(pm[0][j2 * 2], pm[1][j2 * 2]), fmaxf(pm[2][j2 * 2], pm[3][j2 * 2]));
        float c = fmaxf(fmaxf(pm[0][j2 * 2 + 1], pm[1][j2 * 2 + 1]), fmaxf(pm[2][j2 * 2 + 1], pm[3][j2 * 2 + 1]));
        *(float2*)(pmax + (size_t)blockIdx.x * HID + j2 * 2) = make_float2(a, c);
    }
}

// ---------------- classifier ----------------
__global__ __launch_bounds__(128) void clf_k(const float* __restrict__ pmax,
                                             const float* __restrict__ W,
                                             const float* __restrict__ b,
                                             float* __restrict__ out) {
    __shared__ float red[2];
    const int g = blockIdx.x;
    const int t = threadIdx.x;
    float m = -INFINITY;
    #pragma unroll
    for (int p = 0; p < POOL_P; ++p)
        m = fmaxf(m, pmax[((size_t)g * POOL_P + p) * HID + t]);
    float v = m * W[t];
    #pragma unroll
    for (int off = 32; off >= 1; off >>= 1) v += __shfl_down(v, off, 64);
    if ((t & 63) == 0) red[t >> 6] = v;
    __syncthreads();
    if (t == 0) {
        float s = red[0] + red[1] + b[0];
        out[g] = 1.f / (1.f + expf(-s));
    }
}

extern "C" void kernel_launch(void* const* d_in, const int* in_sizes, int n_in,
                              void* d_out, int out_size, void* d_ws, size_t ws_size,
                              hipStream_t stream) {
    const int* x      = (const int*)d_in[0];
    const int* ei     = (const int*)d_in[1];
    const int* batch  = (const int*)d_in[2];
    const float* emb  = (const float*)d_in[3];
    const float* Wih0 = (const float*)d_in[4];
    const float* Whh0 = (const float*)d_in[5];
    const float* bih0 = (const float*)d_in[6];
    const float* bhh0 = (const float*)d_in[7];
    const float* Wih1 = (const float*)d_in[8];
    const float* Whh1 = (const float*)d_in[9];
    const float* bih1 = (const float*)d_in[10];
    const float* bhh1 = (const float*)d_in[11];
    const float* dW   = (const float*)d_in[12];
    const float* db   = (const float*)d_in[13];
    const float* cW   = (const float*)d_in[14];
    const float* cb   = (const float*)d_in[15];

    const int N = in_sizes[0];          // 100000
    const int E = in_sizes[1] / 2;      // 1600000
    const int NG = out_size;            // 128
    const size_t NH = (size_t)N * HID;
    const int NPB = (N + NPART - 1) / NPART;          // bins/partition (12500 <= MAXBIN)
    const int ECH = (E + NCHUNK - 1) / NCHUNK;        // edges/chunk

    short* hb0 = (short*)d_ws;                        // NH bf16
    short* hb1 = hb0 + NH;                            // NH bf16 (agg)
    short* hb2 = hb1 + NH;                            // NH bf16
    short* P0  = hb2 + NH;
    short* P1  = P0 + 48 * 4 * 64 * 8;
    short* Pd  = P1 + 48 * 4 * 64 * 8;
    float* pmax = (float*)(Pd + 8 * 4 * 64 * 8);      // NG*POOL_P*HID
    int* bflag      = (int*)(pmax + (size_t)NG * POOL_P * HID);  // 64
    int* bsum       = bflag + 64;                     // 64
    int* degsum     = bsum + 64;                      // N
    int* rowstart   = degsum + N;                     // N+4
    int* ghist      = rowstart + (N + 4);             // NPART*NCHUNK*NPB
    int* sorted_src = ghist + (size_t)NPART * NCHUNK * NPB;  // E

    const int* esrc = ei;
    const int* edst = ei + E;

    dim3 blk(256);
    int embGrid256  = (N * 16 + 255) / 256;
    int embGrid1024 = (N * 16 + 1023) / 1024;
    int tileGrid = (N + 15) / 16;
    const int scanBlocks = (N + 4095) / 4096;   // 25 <= 64

    // weight packing
    pack_all_k<<<104, blk, 0, stream>>>(Wih0, Whh0, Wih1, Whh1, dW, P0, P1, Pd);

    // embed + LDS radix histogram (zero global atomics), 1024-thread blocks
    hipMemsetAsync(bflag, 0, 64 * sizeof(int), stream);
    radix_embed_k<<<NPART * NCHUNK + embGrid1024, dim3(1024), 0, stream>>>(
        x, emb, hb0, N, edst, ghist, E, NPB, ECH);

    // per-node chunk bases + degree, then lookback scan, then LDS-cursor fill
    chunksum_k<<<(N + 255) / 256, blk, 0, stream>>>(ghist, degsum, N, NPB);
    scan_k<<<scanBlocks, dim3(1024), 0, stream>>>(degsum, rowstart, N, bsum, bflag, scanBlocks);
    fill2_k<<<NPART * NCHUNK, dim3(1024), 0, stream>>>(esrc, edst, rowstart, ghist, sorted_src,
                                                       E, N, NPB, ECH);

    // layer 0
    gather_k<<<embGrid256, blk, 0, stream>>>(rowstart, sorted_src, hb0, hb1, N);
    gru_mfma_k<<<tileGrid, blk, 0, stream>>>(hb1, hb0, hb2, P0, bih0, bhh0, N);

    // layer 1 (+ dense fused)
    gather_k<<<embGrid256, blk, 0, stream>>>(rowstart, sorted_src, hb2, hb1, N);
    gru_dense_k<<<tileGrid, blk, 0, stream>>>(hb1, hb2, hb0, P1, bih1, bhh1, Pd, db, N);

    // pool + classifier
    pool_k<<<NG * POOL_P, blk, 0, stream>>>(hb0, batch, N, pmax);
    clf_k<<<NG, dim3(128), 0, stream>>>(pmax, cW, cb, (float*)d_out);
}

// Round 10
// 439.965 us; speedup vs baseline: 1.3090x; 1.0279x over previous
//
#include <hip/hip_runtime.h>
#include <hip/hip_bf16.h>
#include <math.h>

#define HID 128
#define POOL_P 4
#define NPART 8
#define NCHUNK 32
#define MAXBIN 12544   // LDS bins per partition (>= ceil(N/8)); 50.2 KB
#define FSLAB 520      // fragment slab stride in shorts (512 + 8 pad)

typedef __attribute__((ext_vector_type(8))) short bf16x8;
typedef __attribute__((ext_vector_type(4))) float f32x4;
typedef __attribute__((ext_vector_type(4))) int int4v;

__device__ __forceinline__ short f2bf(float f) {
    unsigned int u = __float_as_uint(f);
    u += 0x7FFF + ((u >> 16) & 1);   // RNE
    return (short)(u >> 16);
}
__device__ __forceinline__ float bf2f(short s) {
    return __uint_as_float(((unsigned int)(unsigned short)s) << 16);
}

// raw-transcendental gate math (v_exp_f32/v_rcp_f32; s_nop covers TRANS-use hazard)
__device__ __forceinline__ float fexp2(float x) {
    float r;
    asm("v_exp_f32 %0, %1\n\ts_nop 0" : "=v"(r) : "v"(x));
    return r;
}
__device__ __forceinline__ float frcp(float x) {
    float r;
    asm("v_rcp_f32 %0, %1\n\ts_nop 0" : "=v"(r) : "v"(x));
    return r;
}
__device__ __forceinline__ float fsigmoid(float x) {
    return frcp(1.f + fexp2(-1.44269504f * x));
}
__device__ __forceinline__ float ftanh(float x) {
    return 1.f - 2.f * frcp(1.f + fexp2(2.88539008f * x));
}

// ------- fused (1024 thr): blocks [0,256) per-(part,chunk) LDS histograms; rest embed -------
__global__ __launch_bounds__(1024) void radix_embed_k(const int* __restrict__ x,
                                                      const float* __restrict__ emb,
                                                      short* __restrict__ h, int nnodes,
                                                      const int* __restrict__ dst,
                                                      int* __restrict__ ghist,
                                                      int nedges, int NPB, int ECH) {
    __shared__ int lh[MAXBIN];
    const int t = threadIdx.x;
    if ((int)blockIdx.x < NPART * NCHUNK) {
        const int part = blockIdx.x & (NPART - 1);
        const int chunk = blockIdx.x >> 3;
        const int lo = part * NPB;
        const int hi = min(lo + NPB, nnodes);
        const int nb = hi - lo;
        for (int b = t; b < nb; b += 1024) lh[b] = 0;
        __syncthreads();
        const int e0 = chunk * ECH;
        const int e1 = min(nedges, e0 + ECH);
        for (int base = e0; base < e1; base += 4096) {
            int e = base + (t << 2);
            if (e + 4 <= e1) {
                int4v d4 = *(const int4v*)(dst + e);
                #pragma unroll
                for (int k = 0; k < 4; ++k) {
                    int d = d4[k];
                    if (d >= lo && d < hi) atomicAdd(&lh[d - lo], 1);
                }
            } else {
                for (int k = 0; k < 4 && e + k < e1; ++k) {
                    int d = dst[e + k];
                    if (d >= lo && d < hi) atomicAdd(&lh[d - lo], 1);
                }
            }
        }
        __syncthreads();
        int* out = ghist + (size_t)blockIdx.x * NPB;
        for (int b = t; b < nb; b += 1024) out[b] = lh[b];
    } else {
        int bi = blockIdx.x - NPART * NCHUNK;
        int tid = bi * 1024 + t;
        int node = tid >> 4;
        int c8 = tid & 15;
        if (node >= nnodes) return;
        int tok = x[node];
        float4 f0 = ((const float4*)emb)[(size_t)tok * 32 + c8 * 2];
        float4 f1 = ((const float4*)emb)[(size_t)tok * 32 + c8 * 2 + 1];
        bf16x8 o;
        o[0] = f2bf(f0.x); o[1] = f2bf(f0.y); o[2] = f2bf(f0.z); o[3] = f2bf(f0.w);
        o[4] = f2bf(f1.x); o[5] = f2bf(f1.y); o[6] = f2bf(f1.z); o[7] = f2bf(f1.w);
        *(bf16x8*)(h + (size_t)node * HID + c8 * 8) = o;
    }
}

// ------- per-node chunk-exclusive prefix (in place) + total degree -------
__global__ __launch_bounds__(256) void chunksum_k(int* __restrict__ ghist,
                                                  int* __restrict__ degsum,
                                                  int nnodes, int NPB) {
    int node = blockIdx.x * 256 + threadIdx.x;
    if (node >= nnodes) return;
    int part = node / NPB;
    int bin = node - part * NPB;
    int running = 0;
    #pragma unroll 4
    for (int c = 0; c < NCHUNK; ++c) {
        size_t idx = (size_t)(part + NPART * c) * NPB + bin;
        int v = ghist[idx];
        ghist[idx] = running;
        running += v;
    }
    degsum[node] = running;
}

// ------- decoupled-lookback exclusive scan over degsum (blocks <= 64) -------
__global__ __launch_bounds__(1024) void scan_k(const int* __restrict__ deg,
                                               int* __restrict__ rowstart,
                                               int n, int* bsum, int* bflag, int nblocks) {
    __shared__ int wsum[16];
    __shared__ int prefix_s, total_s;
    const int b = blockIdx.x;
    const int t = threadIdx.x, lane = t & 63, w = t >> 6;
    const int i4 = b * 4096 + t * 4;
    int4 v = make_int4(0, 0, 0, 0);
    if (i4 + 3 < n) v = *(const int4*)(deg + i4);
    else if (i4 < n) {
        v.x = deg[i4];
        if (i4 + 1 < n) v.y = deg[i4 + 1];
        if (i4 + 2 < n) v.z = deg[i4 + 2];
    }
    int s1 = v.x + v.y, s2 = s1 + v.z, s3 = s2 + v.w;
    int sum = s3;
    #pragma unroll
    for (int off = 1; off < 64; off <<= 1) {
        int o = __shfl_up(sum, off, 64);
        if (lane >= off) sum += o;
    }
    if (lane == 63) wsum[w] = sum;
    __syncthreads();
    if (t == 0) {
        int run = 0;
        #pragma unroll
        for (int k = 0; k < 16; ++k) { int xx = wsum[k]; wsum[k] = run; run += xx; }
        total_s = run;
        atomicExch(&bsum[b], run);
        __threadfence();
        atomicExch(&bflag[b], 1);
    }
    __syncthreads();
    if (w == 0) {
        int p = 0;
        if (lane < b) {
            while (atomicAdd(&bflag[lane], 0) == 0) {}
            p = atomicAdd(&bsum[lane], 0);
        }
        #pragma unroll
        for (int off = 32; off >= 1; off >>= 1) p += __shfl_down(p, off, 64);
        if (lane == 0) prefix_s = p;
    }
    __syncthreads();
    const int excl = (sum - s3) + wsum[w] + prefix_s;
    if (i4 + 3 < n) {
        *(int4*)(rowstart + i4) = make_int4(excl, excl + v.x, excl + s1, excl + s2);
    } else if (i4 < n) {
        rowstart[i4] = excl;
        if (i4 + 1 < n) rowstart[i4 + 1] = excl + v.x;
        if (i4 + 2 < n) rowstart[i4 + 2] = excl + s1;
    }
    if (b == nblocks - 1 && t == 1023) rowstart[n] = prefix_s + total_s;
}

// ------- fill via LDS cursors (1024 thr): zero global atomics, cached edge reads -------
__global__ __launch_bounds__(1024) void fill2_k(const int* __restrict__ src,
                                                const int* __restrict__ dst,
                                                const int* __restrict__ rowstart,
                                                const int* __restrict__ ghist,
                                                int* __restrict__ sorted_src,
                                                int nedges, int nnodes, int NPB, int ECH) {
    __shared__ int cur[MAXBIN];
    const int t = threadIdx.x;
    const int part = blockIdx.x & (NPART - 1);
    const int chunk = blockIdx.x >> 3;
    const int lo = part * NPB;
    const int hi = min(lo + NPB, nnodes);
    const int nb = hi - lo;
    const int* base = ghist + (size_t)blockIdx.x * NPB;
    for (int b = t; b < nb; b += 1024)
        cur[b] = rowstart[lo + b] + base[b];
    __syncthreads();
    const int e0 = chunk * ECH;
    const int e1 = min(nedges, e0 + ECH);
    for (int bb = e0; bb < e1; bb += 4096) {
        int e = bb + (t << 2);
        if (e + 4 <= e1) {
            int4v d4 = *(const int4v*)(dst + e);
            #pragma unroll
            for (int k = 0; k < 4; ++k) {
                int d = d4[k];
                if (d >= lo && d < hi) {
                    int s = src[e + k];
                    int pos = atomicAdd(&cur[d - lo], 1);   // LDS atomic
                    sorted_src[pos] = s;
                }
            }
        } else {
            for (int k = 0; k < 4 && e + k < e1; ++k) {
                int d = dst[e + k];
                if (d >= lo && d < hi) {
                    int s = src[e + k];
                    int pos = atomicAdd(&cur[d - lo], 1);
                    sorted_src[pos] = s;
                }
            }
        }
    }
}

// ---------------- gather-aggregate (bf16 h), 4-deep MLP ----------------
__global__ __launch_bounds__(256) void gather_k(const int* __restrict__ rowstart,
                                                const int* __restrict__ sorted_src,
                                                const short* __restrict__ h,
                                                short* __restrict__ agg, int nnodes) {
    int tid = blockIdx.x * 256 + threadIdx.x;
    int node = tid >> 4;
    int l = tid & 15;
    if (node >= nnodes) return;
    int beg = rowstart[node];
    int end = rowstart[node + 1];
    const bf16x8* hr = (const bf16x8*)h;
    float a[8];
    #pragma unroll
    for (int i = 0; i < 8; ++i) a[i] = 0.f;
    int e = beg;
    for (; e + 4 <= end; e += 4) {
        int s0 = sorted_src[e];
        int s1 = sorted_src[e + 1];
        int s2 = sorted_src[e + 2];
        int s3 = sorted_src[e + 3];
        bf16x8 v0 = hr[(size_t)s0 * 16 + l];
        bf16x8 v1 = hr[(size_t)s1 * 16 + l];
        bf16x8 v2 = hr[(size_t)s2 * 16 + l];
        bf16x8 v3 = hr[(size_t)s3 * 16 + l];
        #pragma unroll
        for (int i = 0; i < 8; ++i) a[i] += bf2f(v0[i]);
        #pragma unroll
        for (int i = 0; i < 8; ++i) a[i] += bf2f(v1[i]);
        #pragma unroll
        for (int i = 0; i < 8; ++i) a[i] += bf2f(v2[i]);
        #pragma unroll
        for (int i = 0; i < 8; ++i) a[i] += bf2f(v3[i]);
    }
    for (; e < end; ++e) {
        bf16x8 v0 = hr[(size_t)sorted_src[e] * 16 + l];
        #pragma unroll
        for (int i = 0; i < 8; ++i) a[i] += bf2f(v0[i]);
    }
    bf16x8 o;
    #pragma unroll
    for (int i = 0; i < 8; ++i) o[i] = f2bf(a[i]);
    *(bf16x8*)(agg + (size_t)node * HID + l * 8) = o;
}

// ---------------- weight pack: all three weight sets in one launch ----------------
__global__ __launch_bounds__(256) void pack_all_k(const float* __restrict__ Wih0,
                                                  const float* __restrict__ Whh0,
                                                  const float* __restrict__ Wih1,
                                                  const float* __restrict__ Whh1,
                                                  const float* __restrict__ dW,
                                                  short* __restrict__ P0,
                                                  short* __restrict__ P1,
                                                  short* __restrict__ Pd) {
    int b = blockIdx.x;
    const float* WA; const float* WB; short* P; int ntilesA; int tile;
    if (b < 48)      { WA = Wih0; WB = Whh0; P = P0; ntilesA = 24; tile = b; }
    else if (b < 96) { WA = Wih1; WB = Whh1; P = P1; ntilesA = 24; tile = b - 48; }
    else             { WA = dW;   WB = dW;   P = Pd; ntilesA = 8;  tile = b - 96; }
    const int t = threadIdx.x;
    const int lane = t & 63, k0 = t >> 6;
    const float* W;
    int row;
    if (tile < ntilesA) { W = WA; row = tile * 16 + (lane & 15); }
    else                { W = WB; row = (tile - ntilesA) * 16 + (lane & 15); }
    const int k = k0 * 32 + (lane >> 4) * 8;
    const float4 f0 = *(const float4*)(W + row * HID + k);
    const float4 f1 = *(const float4*)(W + row * HID + k + 4);
    short4 o0 = make_short4(f2bf(f0.x), f2bf(f0.y), f2bf(f0.z), f2bf(f0.w));
    short4 o1 = make_short4(f2bf(f1.x), f2bf(f1.y), f2bf(f1.z), f2bf(f1.w));
    short* dstp = P + ((size_t)(tile * 4 + k0) * 64 + lane) * 8;
    *(short4*)(dstp) = o0;
    *(short4*)(dstp + 4) = o1;
}

// A/H LDS tiles in MFMA fragment layout: slab k0 (FSLAB shorts), lane-contiguous.
// element (row, col): slab = col>>5, pos = ((col>>3)&3)*16 + row, j = col&7.
// MFMA read for slab k0 = As[k0*FSLAB + lane*8] -> conflict-free ds_read_b128.

// ---------------- MFMA fused GRU cell, 16-row tile (bf16 in/out) ----------------
__global__ __launch_bounds__(256) void gru_mfma_k(const short* __restrict__ agg,
                                                  const short* __restrict__ hin,
                                                  short* __restrict__ hout,
                                                  const short* __restrict__ P,
                                                  const float* __restrict__ bih,
                                                  const float* __restrict__ bhh,
                                                  int nnodes) {
    __shared__ short As[4 * FSLAB];
    __shared__ short Hs[4 * FSLAB];
    const int t = threadIdx.x;
    const int mbase = blockIdx.x * 16;
    {
        int row = t >> 4, c8 = t & 15;
        int node = mbase + row;
        bf16x8 a = (bf16x8){0,0,0,0,0,0,0,0};
        bf16x8 hh = (bf16x8){0,0,0,0,0,0,0,0};
        if (node < nnodes) {
            a  = *(const bf16x8*)(agg + (size_t)node * HID + c8 * 8);
            hh = *(const bf16x8*)(hin + (size_t)node * HID + c8 * 8);
        }
        int off = (c8 >> 2) * FSLAB + ((c8 & 3) * 16 + row) * 8;
        *(bf16x8*)&As[off] = a;
        *(bf16x8*)&Hs[off] = hh;
    }
    __syncthreads();

    const int w = t >> 6, lane = t & 63;
    const int ml = lane & 15, kq = lane >> 4;
    const int j0 = w * 32;

    f32x4 acc[12];  // idx = (mat*3 + gate)*2 + ctt
    #pragma unroll
    for (int i = 0; i < 12; ++i) acc[i] = (f32x4){0.f, 0.f, 0.f, 0.f};

    const short* Pb = P + (size_t)lane * 8;

    #pragma unroll
    for (int k0 = 0; k0 < 4; ++k0) {
        bf16x8 aa = *(const bf16x8*)&As[k0 * FSLAB + lane * 8];
        bf16x8 ah = *(const bf16x8*)&Hs[k0 * FSLAB + lane * 8];
        #pragma unroll
        for (int m = 0; m < 2; ++m) {
            #pragma unroll
            for (int g = 0; g < 3; ++g) {
                #pragma unroll
                for (int ctt = 0; ctt < 2; ++ctt) {
                    const int tile = m * 24 + g * 8 + (w << 1) + ctt;
                    bf16x8 bb = *(const bf16x8*)(Pb + (size_t)(tile * 4 + k0) * 512);
                    const int idx = (m * 3 + g) * 2 + ctt;
                    acc[idx] = __builtin_amdgcn_mfma_f32_16x16x32_bf16(
                        (m == 0) ? aa : ah, bb, acc[idx], 0, 0, 0);
                }
            }
        }
    }

    #pragma unroll
    for (int ctt = 0; ctt < 2; ++ctt) {
        const int col = j0 + ctt * 16 + ml;
        const float b_ir = bih[col], b_iz = bih[col + 128], b_in = bih[col + 256];
        const float b_hr = bhh[col], b_hz = bhh[col + 128], b_hn = bhh[col + 256];
        const int hbase = w * FSLAB + (2 * ctt + (ml >> 3)) * 128 + (ml & 7);
        #pragma unroll
        for (int r = 0; r < 4; ++r) {
            const int row = kq * 4 + r;
            const int node = mbase + row;
            float ir = acc[0 + ctt][r] + b_ir;
            float iz = acc[2 + ctt][r] + b_iz;
            float in_ = acc[4 + ctt][r] + b_in;
            float hr = acc[6 + ctt][r] + b_hr;
            float hz = acc[8 + ctt][r] + b_hz;
            float hn = acc[10 + ctt][r] + b_hn;
            float rr = fsigmoid(ir + hr);
            float z  = fsigmoid(iz + hz);
            float n  = ftanh(in_ + rr * hn);
            if (node < nnodes) {
                float hval = bf2f(Hs[hbase + row * 8]);
                hout[(size_t)node * HID + col] = f2bf((1.f - z) * n + z * hval);
            }
        }
    }
}

// ------- layer-1 GRU fused with dense (16-row tile): h' round-trips through LDS -------
__global__ __launch_bounds__(256) void gru_dense_k(const short* __restrict__ agg,
                                                   const short* __restrict__ hin,
                                                   short* __restrict__ yout,
                                                   const short* __restrict__ P,
                                                   const float* __restrict__ bih,
                                                   const float* __restrict__ bhh,
                                                   const short* __restrict__ Pd,
                                                   const float* __restrict__ db,
                                                   int nnodes) {
    __shared__ short As[4 * FSLAB];
    __shared__ short Hs[4 * FSLAB];
    const int t = threadIdx.x;
    const int mbase = blockIdx.x * 16;
    {
        int row = t >> 4, c8 = t & 15;
        int node = mbase + row;
        bf16x8 a = (bf16x8){0,0,0,0,0,0,0,0};
        bf16x8 hh = (bf16x8){0,0,0,0,0,0,0,0};
        if (node < nnodes) {
            a  = *(const bf16x8*)(agg + (size_t)node * HID + c8 * 8);
            hh = *(const bf16x8*)(hin + (size_t)node * HID + c8 * 8);
        }
        int off = (c8 >> 2) * FSLAB + ((c8 & 3) * 16 + row) * 8;
        *(bf16x8*)&As[off] = a;
        *(bf16x8*)&Hs[off] = hh;
    }
    __syncthreads();

    const int w = t >> 6, lane = t & 63;
    const int ml = lane & 15, kq = lane >> 4;
    const int j0 = w * 32;

    f32x4 acc[12];
    #pragma unroll
    for (int i = 0; i < 12; ++i) acc[i] = (f32x4){0.f, 0.f, 0.f, 0.f};

    const short* Pb = P + (size_t)lane * 8;

    #pragma unroll
    for (int k0 = 0; k0 < 4; ++k0) {
        bf16x8 aa = *(const bf16x8*)&As[k0 * FSLAB + lane * 8];
        bf16x8 ah = *(const bf16x8*)&Hs[k0 * FSLAB + lane * 8];
        #pragma unroll
        for (int m = 0; m < 2; ++m) {
            #pragma unroll
            for (int g = 0; g < 3; ++g) {
                #pragma unroll
                for (int ctt = 0; ctt < 2; ++ctt) {
                    const int tile = m * 24 + g * 8 + (w << 1) + ctt;
                    bf16x8 bb = *(const bf16x8*)(Pb + (size_t)(tile * 4 + k0) * 512);
                    const int idx = (m * 3 + g) * 2 + ctt;
                    acc[idx] = __builtin_amdgcn_mfma_f32_16x16x32_bf16(
                        (m == 0) ? aa : ah, bb, acc[idx], 0, 0, 0);
                }
            }
        }
    }

    // GRU epilogue -> h' in registers
    short hnew[2][4];
    #pragma unroll
    for (int ctt = 0; ctt < 2; ++ctt) {
        const int col = j0 + ctt * 16 + ml;
        const float b_ir = bih[col], b_iz = bih[col + 128], b_in = bih[col + 256];
        const float b_hr = bhh[col], b_hz = bhh[col + 128], b_hn = bhh[col + 256];
        const int hbase = w * FSLAB + (2 * ctt + (ml >> 3)) * 128 + (ml & 7);
        #pragma unroll
        for (int r = 0; r < 4; ++r) {
            const int row = kq * 4 + r;
            float ir = acc[0 + ctt][r] + b_ir;
            float iz = acc[2 + ctt][r] + b_iz;
            float in_ = acc[4 + ctt][r] + b_in;
            float hr = acc[6 + ctt][r] + b_hr;
            float hz = acc[8 + ctt][r] + b_hz;
            float hn = acc[10 + ctt][r] + b_hn;
            float rr = fsigmoid(ir + hr);
            float z  = fsigmoid(iz + hz);
            float n  = ftanh(in_ + rr * hn);
            float hval = bf2f(Hs[hbase + row * 8]);
            hnew[ctt][r] = f2bf((1.f - z) * n + z * hval);
        }
    }

    __syncthreads();   // all waves finished reading As/Hs
    // store h' into fragment layout for the dense MFMA
    #pragma unroll
    for (int ctt = 0; ctt < 2; ++ctt) {
        const int hbase = w * FSLAB + (2 * ctt + (ml >> 3)) * 128 + (ml & 7);
        #pragma unroll
        for (int r = 0; r < 4; ++r)
            As[hbase + (kq * 4 + r) * 8] = hnew[ctt][r];
    }
    __syncthreads();

    // dense phase: y = h' @ dW.T + db
    f32x4 dacc[2];
    dacc[0] = (f32x4){0.f, 0.f, 0.f, 0.f};
    dacc[1] = (f32x4){0.f, 0.f, 0.f, 0.f};
    const short* Pbd = Pd + (size_t)lane * 8;
    #pragma unroll
    for (int k0 = 0; k0 < 4; ++k0) {
        bf16x8 aa = *(const bf16x8*)&As[k0 * FSLAB + lane * 8];
        #pragma unroll
        for (int ctt = 0; ctt < 2; ++ctt) {
            const int tile = (w << 1) + ctt;
            bf16x8 bb = *(const bf16x8*)(Pbd + (size_t)(tile * 4 + k0) * 512);
            dacc[ctt] = __builtin_amdgcn_mfma_f32_16x16x32_bf16(aa, bb, dacc[ctt], 0, 0, 0);
        }
    }
    #pragma unroll
    for (int ctt = 0; ctt < 2; ++ctt) {
        const int col = j0 + ctt * 16 + ml;
        const float bias = db[col];
        #pragma unroll
        for (int r = 0; r < 4; ++r) {
            const int node = mbase + kq * 4 + r;
            if (node < nnodes)
                yout[(size_t)node * HID + col] = f2bf(dacc[ctt][r] + bias);
        }
    }
}

// ---------------- segment max pool, 4-way split per graph ----------------
__global__ __launch_bounds__(256) void pool_k(const short* __restrict__ xh,
                                              const int* __restrict__ batch,
                                              int nnodes, float* __restrict__ pmax) {
    const int g = blockIdx.x >> 2;
    const int p = blockIdx.x & (POOL_P - 1);
    int lo = 0, hi = nnodes;
    while (lo < hi) { int mid = (lo + hi) >> 1; if (batch[mid] < g) lo = mid + 1; else hi = mid; }
    int start = lo;
    lo = 0; hi = nnodes;
    while (lo < hi) { int mid = (lo + hi) >> 1; if (batch[mid] < g + 1) lo = mid + 1; else hi = mid; }
    int end = lo;
    int len = end - start;
    int q0 = start + (int)(((long long)len * p) / POOL_P);
    int q1 = start + (int)(((long long)len * (p + 1)) / POOL_P);

    const int rg = threadIdx.x >> 6;
    const int j2 = threadIdx.x & 63;
    float m0 = -INFINITY, m1 = -INFINITY;
    for (int i = q0 + rg; i < q1; i += 4) {
        unsigned int u = *(const unsigned int*)(xh + (size_t)i * HID + j2 * 2);
        m0 = fmaxf(m0, __uint_as_float(u << 16));
        m1 = fmaxf(m1, __uint_as_float(u & 0xFFFF0000u));
    }
    __shared__ float pm[4][130];
    pm[rg][j2 * 2] = m0;
    pm[rg][j2 * 2 + 1] = m1;
    __syncthreads();
    if (rg == 0) {
        float a = fmaxf(fmaxf(pm[0][j2 * 2], pm[1][j2 * 2]), fmaxf(pm[2][j2 * 2], pm[3][j2 * 2]));
        float c = fmaxf(fmaxf(pm[0][j2 * 2 + 1], pm[1][j2 * 2 + 1]), fmaxf(pm[2][j2 * 2 + 1], pm[3][j2 * 2 + 1]));
        *(float2*)(pmax + (size_t)blockIdx.x * HID + j2 * 2) = make_float2(a, c);
    }
}

// ---------------- classifier ----------------
__global__ __launch_bounds__(128) void clf_k(const float* __restrict__ pmax,
                                             const float* __restrict__ W,
                                             const float* __restrict__ b,
                                             float* __restrict__ out) {
    __shared__ float red[2];
    const int g = blockIdx.x;
    const int t = threadIdx.x;
    float m = -INFINITY;
    #pragma unroll
    for (int p = 0; p < POOL_P; ++p)
        m = fmaxf(m, pmax[((size_t)g * POOL_P + p) * HID + t]);
    float v = m * W[t];
    #pragma unroll
    for (int off = 32; off >= 1; off >>= 1) v += __shfl_down(v, off, 64);
    if ((t & 63) == 0) red[t >> 6] = v;
    __syncthreads();
    if (t == 0) {
        float s = red[0] + red[1] + b[0];
        out[g] = 1.f / (1.f + expf(-s));
    }
}

extern "C" void kernel_launch(void* const* d_in, const int* in_sizes, int n_in,
                              void* d_out, int out_size, void* d_ws, size_t ws_size,
                              hipStream_t stream) {
    const int* x      = (const int*)d_in[0];
    const int* ei     = (const int*)d_in[1];
    const int* batch  = (const int*)d_in[2];
    const float* emb  = (const float*)d_in[3];
    const float* Wih0 = (const float*)d_in[4];
    const float* Whh0 = (const float*)d_in[5];
    const float* bih0 = (const float*)d_in[6];
    const float* bhh0 = (const float*)d_in[7];
    const float* Wih1 = (const float*)d_in[8];
    const float* Whh1 = (const float*)d_in[9];
    const float* bih1 = (const float*)d_in[10];
    const float* bhh1 = (const float*)d_in[11];
    const float* dW   = (const float*)d_in[12];
    const float* db   = (const float*)d_in[13];
    const float* cW   = (const float*)d_in[14];
    const float* cb   = (const float*)d_in[15];

    const int N = in_sizes[0];          // 100000
    const int E = in_sizes[1] / 2;      // 1600000
    const int NG = out_size;            // 128
    const size_t NH = (size_t)N * HID;
    const int NPB = (N + NPART - 1) / NPART;
    const int ECH = (E + NCHUNK - 1) / NCHUNK;

    short* hb0 = (short*)d_ws;                        // NH bf16
    short* hb1 = hb0 + NH;                            // NH bf16 (agg)
    short* hb2 = hb1 + NH;                            // NH bf16
    short* P0  = hb2 + NH;
    short* P1  = P0 + 48 * 4 * 64 * 8;
    short* Pd  = P1 + 48 * 4 * 64 * 8;
    float* pmax = (float*)(Pd + 8 * 4 * 64 * 8);      // NG*POOL_P*HID
    int* bflag      = (int*)(pmax + (size_t)NG * POOL_P * HID);  // 64
    int* bsum       = bflag + 64;                     // 64
    int* degsum     = bsum + 64;                      // N
    int* rowstart   = degsum + N;                     // N+4
    int* ghist      = rowstart + (N + 4);             // NPART*NCHUNK*NPB
    int* sorted_src = ghist + (size_t)NPART * NCHUNK * NPB;  // E

    const int* esrc = ei;
    const int* edst = ei + E;

    dim3 blk(256);
    int embGrid256  = (N * 16 + 255) / 256;
    int embGrid1024 = (N * 16 + 1023) / 1024;
    int tileGrid = (N + 15) / 16;
    const int scanBlocks = (N + 4095) / 4096;   // 25 <= 64

    // weight packing
    pack_all_k<<<104, blk, 0, stream>>>(Wih0, Whh0, Wih1, Whh1, dW, P0, P1, Pd);

    // embed + LDS radix histogram (zero global atomics)
    hipMemsetAsync(bflag, 0, 64 * sizeof(int), stream);
    radix_embed_k<<<NPART * NCHUNK + embGrid1024, dim3(1024), 0, stream>>>(
        x, emb, hb0, N, edst, ghist, E, NPB, ECH);

    // per-node chunk bases + degree, then lookback scan, then LDS-cursor fill
    chunksum_k<<<(N + 255) / 256, blk, 0, stream>>>(ghist, degsum, N, NPB);
    scan_k<<<scanBlocks, dim3(1024), 0, stream>>>(degsum, rowstart, N, bsum, bflag, scanBlocks);
    fill2_k<<<NPART * NCHUNK, dim3(1024), 0, stream>>>(esrc, edst, rowstart, ghist, sorted_src,
                                                       E, N, NPB, ECH);

    // layer 0
    gather_k<<<embGrid256, blk, 0, stream>>>(rowstart, sorted_src, hb0, hb1, N);
    gru_mfma_k<<<tileGrid, blk, 0, stream>>>(hb1, hb0, hb2, P0, bih0, bhh0, N);

    // layer 1 (+ dense fused)
    gather_k<<<embGrid256, blk, 0, stream>>>(rowstart, sorted_src, hb2, hb1, N);
    gru_dense_k<<<tileGrid, blk, 0, stream>>>(hb1, hb2, hb0, P1, bih1, bhh1, Pd, db, N);

    // pool + classifier
    pool_k<<<NG * POOL_P, blk, 0, stream>>>(hb0, batch, N, pmax);
    clf_k<<<NG, dim3(128), 0, stream>>>(pmax, cW, cb, (float*)d_out);
}

// Round 11
// 399.606 us; speedup vs baseline: 1.4412x; 1.1010x over previous
//
#include <hip/hip_runtime.h>
#include <hip/hip_bf16.h>
#include <math.h>

#define HID 128
#define POOL_P 4
#define NPART 8
#define NCHUNK 32
#define MAXBIN 12544   // LDS bins per partition (>= ceil(N/8)); 50.2 KB
#define FSLAB 520      // fragment slab stride in shorts (512 + 8 pad)

typedef __attribute__((ext_vector_type(8))) short bf16x8;
typedef __attribute__((ext_vector_type(4))) float f32x4;
typedef __attribute__((ext_vector_type(4))) int int4v;

__device__ __forceinline__ short f2bf(float f) {
    unsigned int u = __float_as_uint(f);
    u += 0x7FFF + ((u >> 16) & 1);   // RNE
    return (short)(u >> 16);
}
__device__ __forceinline__ float bf2f(short s) {
    return __uint_as_float(((unsigned int)(unsigned short)s) << 16);
}

// raw-transcendental gate math
__device__ __forceinline__ float fexp2(float x) {
    float r;
    asm("v_exp_f32 %0, %1\n\ts_nop 0" : "=v"(r) : "v"(x));
    return r;
}
__device__ __forceinline__ float frcp(float x) {
    float r;
    asm("v_rcp_f32 %0, %1\n\ts_nop 0" : "=v"(r) : "v"(x));
    return r;
}
__device__ __forceinline__ float fsigmoid(float x) {
    return frcp(1.f + fexp2(-1.44269504f * x));
}
__device__ __forceinline__ float ftanh(float x) {
    return 1.f - 2.f * frcp(1.f + fexp2(2.88539008f * x));
}

// ------- fused (1024 thr): blocks [0,256) per-(part,chunk) LDS histograms; rest embed -------
__global__ __launch_bounds__(1024) void radix_embed_k(const int* __restrict__ x,
                                                      const float* __restrict__ emb,
                                                      short* __restrict__ h, int nnodes,
                                                      const int* __restrict__ dst,
                                                      int* __restrict__ ghist,
                                                      int nedges, int NPB, int ECH) {
    __shared__ int lh[MAXBIN];
    const int t = threadIdx.x;
    if ((int)blockIdx.x < NPART * NCHUNK) {
        const int part = blockIdx.x & (NPART - 1);
        const int chunk = blockIdx.x >> 3;
        const int lo = part * NPB;
        const int hi = min(lo + NPB, nnodes);
        const int nb = hi - lo;
        for (int b = t; b < nb; b += 1024) lh[b] = 0;
        __syncthreads();
        const int e0 = chunk * ECH;
        const int e1 = min(nedges, e0 + ECH);
        for (int base = e0; base < e1; base += 4096) {
            int e = base + (t << 2);
            if (e + 4 <= e1) {
                int4v d4 = *(const int4v*)(dst + e);
                #pragma unroll
                for (int k = 0; k < 4; ++k) {
                    int d = d4[k];
                    if (d >= lo && d < hi) atomicAdd(&lh[d - lo], 1);
                }
            } else {
                for (int k = 0; k < 4 && e + k < e1; ++k) {
                    int d = dst[e + k];
                    if (d >= lo && d < hi) atomicAdd(&lh[d - lo], 1);
                }
            }
        }
        __syncthreads();
        int* out = ghist + (size_t)blockIdx.x * NPB;
        for (int b = t; b < nb; b += 1024) out[b] = lh[b];
    } else {
        int bi = blockIdx.x - NPART * NCHUNK;
        int tid = bi * 1024 + t;
        int node = tid >> 4;
        int c8 = tid & 15;
        if (node >= nnodes) return;
        int tok = x[node];
        float4 f0 = ((const float4*)emb)[(size_t)tok * 32 + c8 * 2];
        float4 f1 = ((const float4*)emb)[(size_t)tok * 32 + c8 * 2 + 1];
        bf16x8 o;
        o[0] = f2bf(f0.x); o[1] = f2bf(f0.y); o[2] = f2bf(f0.z); o[3] = f2bf(f0.w);
        o[4] = f2bf(f1.x); o[5] = f2bf(f1.y); o[6] = f2bf(f1.z); o[7] = f2bf(f1.w);
        *(bf16x8*)(h + (size_t)node * HID + c8 * 8) = o;
    }
}

// ------- per-node chunk-exclusive prefix (in place) + total degree -------
__global__ __launch_bounds__(256) void chunksum_k(int* __restrict__ ghist,
                                                  int* __restrict__ degsum,
                                                  int nnodes, int NPB) {
    int node = blockIdx.x * 256 + threadIdx.x;
    if (node >= nnodes) return;
    int part = node / NPB;
    int bin = node - part * NPB;
    int running = 0;
    #pragma unroll 4
    for (int c = 0; c < NCHUNK; ++c) {
        size_t idx = (size_t)(part + NPART * c) * NPB + bin;
        int v = ghist[idx];
        ghist[idx] = running;
        running += v;
    }
    degsum[node] = running;
}

// ------- decoupled-lookback exclusive scan over degsum (blocks <= 64) -------
__global__ __launch_bounds__(1024) void scan_k(const int* __restrict__ deg,
                                               int* __restrict__ rowstart,
                                               int n, int* bsum, int* bflag, int nblocks) {
    __shared__ int wsum[16];
    __shared__ int prefix_s, total_s;
    const int b = blockIdx.x;
    const int t = threadIdx.x, lane = t & 63, w = t >> 6;
    const int i4 = b * 4096 + t * 4;
    int4 v = make_int4(0, 0, 0, 0);
    if (i4 + 3 < n) v = *(const int4*)(deg + i4);
    else if (i4 < n) {
        v.x = deg[i4];
        if (i4 + 1 < n) v.y = deg[i4 + 1];
        if (i4 + 2 < n) v.z = deg[i4 + 2];
    }
    int s1 = v.x + v.y, s2 = s1 + v.z, s3 = s2 + v.w;
    int sum = s3;
    #pragma unroll
    for (int off = 1; off < 64; off <<= 1) {
        int o = __shfl_up(sum, off, 64);
        if (lane >= off) sum += o;
    }
    if (lane == 63) wsum[w] = sum;
    __syncthreads();
    if (t == 0) {
        int run = 0;
        #pragma unroll
        for (int k = 0; k < 16; ++k) { int xx = wsum[k]; wsum[k] = run; run += xx; }
        total_s = run;
        atomicExch(&bsum[b], run);
        __threadfence();
        atomicExch(&bflag[b], 1);
    }
    __syncthreads();
    if (w == 0) {
        int p = 0;
        if (lane < b) {
            while (atomicAdd(&bflag[lane], 0) == 0) {}
            p = atomicAdd(&bsum[lane], 0);
        }
        #pragma unroll
        for (int off = 32; off >= 1; off >>= 1) p += __shfl_down(p, off, 64);
        if (lane == 0) prefix_s = p;
    }
    __syncthreads();
    const int excl = (sum - s3) + wsum[w] + prefix_s;
    if (i4 + 3 < n) {
        *(int4*)(rowstart + i4) = make_int4(excl, excl + v.x, excl + s1, excl + s2);
    } else if (i4 < n) {
        rowstart[i4] = excl;
        if (i4 + 1 < n) rowstart[i4 + 1] = excl + v.x;
        if (i4 + 2 < n) rowstart[i4 + 2] = excl + s1;
    }
    if (b == nblocks - 1 && t == 1023) rowstart[n] = prefix_s + total_s;
}

// ------- fill via LDS cursors (1024 thr): zero global atomics, cached edge reads -------
__global__ __launch_bounds__(1024) void fill2_k(const int* __restrict__ src,
                                                const int* __restrict__ dst,
                                                const int* __restrict__ rowstart,
                                                const int* __restrict__ ghist,
                                                int* __restrict__ sorted_src,
                                                int nedges, int nnodes, int NPB, int ECH) {
    __shared__ int cur[MAXBIN];
    const int t = threadIdx.x;
    const int part = blockIdx.x & (NPART - 1);
    const int chunk = blockIdx.x >> 3;
    const int lo = part * NPB;
    const int hi = min(lo + NPB, nnodes);
    const int nb = hi - lo;
    const int* base = ghist + (size_t)blockIdx.x * NPB;
    for (int b = t; b < nb; b += 1024)
        cur[b] = rowstart[lo + b] + base[b];
    __syncthreads();
    const int e0 = chunk * ECH;
    const int e1 = min(nedges, e0 + ECH);
    for (int bb = e0; bb < e1; bb += 4096) {
        int e = bb + (t << 2);
        if (e + 4 <= e1) {
            int4v d4 = *(const int4v*)(dst + e);
            #pragma unroll
            for (int k = 0; k < 4; ++k) {
                int d = d4[k];
                if (d >= lo && d < hi) {
                    int s = src[e + k];
                    int pos = atomicAdd(&cur[d - lo], 1);   // LDS atomic
                    sorted_src[pos] = s;
                }
            }
        } else {
            for (int k = 0; k < 4 && e + k < e1; ++k) {
                int d = dst[e + k];
                if (d >= lo && d < hi) {
                    int s = src[e + k];
                    int pos = atomicAdd(&cur[d - lo], 1);
                    sorted_src[pos] = s;
                }
            }
        }
    }
}

// ---------------- gather-aggregate (bf16 h), 4-deep MLP ----------------
__global__ __launch_bounds__(256) void gather_k(const int* __restrict__ rowstart,
                                                const int* __restrict__ sorted_src,
                                                const short* __restrict__ h,
                                                short* __restrict__ agg, int nnodes) {
    int tid = blockIdx.x * 256 + threadIdx.x;
    int node = tid >> 4;
    int l = tid & 15;
    if (node >= nnodes) return;
    int beg = rowstart[node];
    int end = rowstart[node + 1];
    const bf16x8* hr = (const bf16x8*)h;
    float a[8];
    #pragma unroll
    for (int i = 0; i < 8; ++i) a[i] = 0.f;
    int e = beg;
    for (; e + 4 <= end; e += 4) {
        int s0 = sorted_src[e];
        int s1 = sorted_src[e + 1];
        int s2 = sorted_src[e + 2];
        int s3 = sorted_src[e + 3];
        bf16x8 v0 = hr[(size_t)s0 * 16 + l];
        bf16x8 v1 = hr[(size_t)s1 * 16 + l];
        bf16x8 v2 = hr[(size_t)s2 * 16 + l];
        bf16x8 v3 = hr[(size_t)s3 * 16 + l];
        #pragma unroll
        for (int i = 0; i < 8; ++i) a[i] += bf2f(v0[i]);
        #pragma unroll
        for (int i = 0; i < 8; ++i) a[i] += bf2f(v1[i]);
        #pragma unroll
        for (int i = 0; i < 8; ++i) a[i] += bf2f(v2[i]);
        #pragma unroll
        for (int i = 0; i < 8; ++i) a[i] += bf2f(v3[i]);
    }
    for (; e < end; ++e) {
        bf16x8 v0 = hr[(size_t)sorted_src[e] * 16 + l];
        #pragma unroll
        for (int i = 0; i < 8; ++i) a[i] += bf2f(v0[i]);
    }
    bf16x8 o;
    #pragma unroll
    for (int i = 0; i < 8; ++i) o[i] = f2bf(a[i]);
    *(bf16x8*)(agg + (size_t)node * HID + l * 8) = o;
}

// ---------------- weight pack: all three weight sets in one launch ----------------
__global__ __launch_bounds__(256) void pack_all_k(const float* __restrict__ Wih0,
                                                  const float* __restrict__ Whh0,
                                                  const float* __restrict__ Wih1,
                                                  const float* __restrict__ Whh1,
                                                  const float* __restrict__ dW,
                                                  short* __restrict__ P0,
                                                  short* __restrict__ P1,
                                                  short* __restrict__ Pd) {
    int b = blockIdx.x;
    const float* WA; const float* WB; short* P; int ntilesA; int tile;
    if (b < 48)      { WA = Wih0; WB = Whh0; P = P0; ntilesA = 24; tile = b; }
    else if (b < 96) { WA = Wih1; WB = Whh1; P = P1; ntilesA = 24; tile = b - 48; }
    else             { WA = dW;   WB = dW;   P = Pd; ntilesA = 8;  tile = b - 96; }
    const int t = threadIdx.x;
    const int lane = t & 63, k0 = t >> 6;
    const float* W;
    int row;
    if (tile < ntilesA) { W = WA; row = tile * 16 + (lane & 15); }
    else                { W = WB; row = (tile - ntilesA) * 16 + (lane & 15); }
    const int k = k0 * 32 + (lane >> 4) * 8;
    const float4 f0 = *(const float4*)(W + row * HID + k);
    const float4 f1 = *(const float4*)(W + row * HID + k + 4);
    short4 o0 = make_short4(f2bf(f0.x), f2bf(f0.y), f2bf(f0.z), f2bf(f0.w));
    short4 o1 = make_short4(f2bf(f1.x), f2bf(f1.y), f2bf(f1.z), f2bf(f1.w));
    short* dstp = P + ((size_t)(tile * 4 + k0) * 64 + lane) * 8;
    *(short4*)(dstp) = o0;
    *(short4*)(dstp + 4) = o1;
}

// LDS fragment layout with swizzle: logical slab position pos = q*16 + row
// (q = k-quad, row = node row) stored at phi(pos) = row*4 + q. MFMA lane l
// reads phi(l) = (l&15)*4 + (l>>4) -> distinct 16B slots (conflict-free);
// staging write is 2-way only (free).

// ------- GRU row-loop kernel: B fragments in registers, double-buffered LDS -------
// Grid = 2*G blocks. blockIdx&1 = col half (waves cover cols ch*64..+63).
// Each block loops row-tiles rt = blockIdx>>1, += G with prefetch.
__global__ __launch_bounds__(256) void gru_rl_k(const short* __restrict__ agg,
                                                const short* __restrict__ hin,
                                                short* __restrict__ hout,
                                                const short* __restrict__ P,
                                                const float* __restrict__ bih,
                                                const float* __restrict__ bhh,
                                                int nnodes, int ntiles) {
    __shared__ short As[2][4 * FSLAB];
    __shared__ short Hs[2][4 * FSLAB];
    const int t = threadIdx.x;
    const int lane = t & 63, w = t >> 6;
    const int ch = blockIdx.x & 1;
    const int cw = ch * 4 + w;          // col-wave 0..7
    const int ml = lane & 15, kq = lane >> 4;
    const int col = cw * 16 + ml;

    const float b_ir = bih[col], b_iz = bih[col + 128], b_in = bih[col + 256];
    const float b_hr = bhh[col], b_hz = bhh[col + 128], b_hn = bhh[col + 256];

    // B fragments in registers: 2 mats x 3 gates x 4 k0 (96 VGPRs)
    bf16x8 B[2][3][4];
    #pragma unroll
    for (int m = 0; m < 2; ++m)
        #pragma unroll
        for (int g = 0; g < 3; ++g)
            #pragma unroll
            for (int k0 = 0; k0 < 4; ++k0)
                B[m][g][k0] = *(const bf16x8*)(P +
                    ((size_t)((m * 24 + g * 8 + cw) * 4 + k0) * 64 + lane) * 8);

    const int srow = t >> 4, sc8 = t & 15;
    const int soff = (sc8 >> 2) * FSLAB + (srow * 4 + (sc8 & 3)) * 8;  // phi-swizzled
    const int roff = (ml * 4 + kq) * 8;                                // phi(l)
    const int hoff = (col >> 5) * FSLAB + ((col >> 3) & 3) * 8 + (col & 7);

    const int rt0 = blockIdx.x >> 1;
    const int stride = gridDim.x >> 1;

    {   // prologue: stage tile rt0 into buf 0
        int node = rt0 * 16 + srow;
        bf16x8 a = (bf16x8){0,0,0,0,0,0,0,0}, hh = a;
        if (node < nnodes) {
            a  = *(const bf16x8*)(agg + (size_t)node * HID + sc8 * 8);
            hh = *(const bf16x8*)(hin + (size_t)node * HID + sc8 * 8);
        }
        *(bf16x8*)&As[0][soff] = a;
        *(bf16x8*)&Hs[0][soff] = hh;
    }
    __syncthreads();

    int buf = 0;
    for (int rt = rt0; rt < ntiles; rt += stride, buf ^= 1) {
        const int nrt = rt + stride;
        bf16x8 pa = (bf16x8){0,0,0,0,0,0,0,0}, ph = pa;
        if (nrt < ntiles) {                 // prefetch next tile (in flight over K-loop)
            int node = nrt * 16 + srow;
            if (node < nnodes) {
                pa = *(const bf16x8*)(agg + (size_t)node * HID + sc8 * 8);
                ph = *(const bf16x8*)(hin + (size_t)node * HID + sc8 * 8);
            }
        }

        f32x4 acc[6];
        #pragma unroll
        for (int i = 0; i < 6; ++i) acc[i] = (f32x4){0.f, 0.f, 0.f, 0.f};
        #pragma unroll
        for (int k0 = 0; k0 < 4; ++k0) {
            bf16x8 aa = *(const bf16x8*)&As[buf][k0 * FSLAB + roff];
            bf16x8 ah = *(const bf16x8*)&Hs[buf][k0 * FSLAB + roff];
            #pragma unroll
            for (int g = 0; g < 3; ++g) {
                acc[g]     = __builtin_amdgcn_mfma_f32_16x16x32_bf16(aa, B[0][g][k0], acc[g], 0, 0, 0);
                acc[3 + g] = __builtin_amdgcn_mfma_f32_16x16x32_bf16(ah, B[1][g][k0], acc[3 + g], 0, 0, 0);
            }
        }

        const int mbase = rt * 16;
        #pragma unroll
        for (int r = 0; r < 4; ++r) {
            const int row = kq * 4 + r;
            const int node = mbase + row;
            float ir = acc[0][r] + b_ir;
            float iz = acc[1][r] + b_iz;
            float in_ = acc[2][r] + b_in;
            float hr = acc[3][r] + b_hr;
            float hz = acc[4][r] + b_hz;
            float hn = acc[5][r] + b_hn;
            float rr = fsigmoid(ir + hr);
            float z  = fsigmoid(iz + hz);
            float n  = ftanh(in_ + rr * hn);
            if (node < nnodes) {
                float hval = bf2f(Hs[buf][hoff + row * 32]);   // (row*4+q)*8 = row*32 + q*8
                hout[(size_t)node * HID + col] = f2bf((1.f - z) * n + z * hval);
            }
        }

        if (nrt < ntiles) {
            *(bf16x8*)&As[buf ^ 1][soff] = pa;
            *(bf16x8*)&Hs[buf ^ 1][soff] = ph;
        }
        __syncthreads();
    }
}

// ------- dense row-loop kernel: y = x @ dW.T + db, B in registers -------
__global__ __launch_bounds__(256) void dense_rl_k(const short* __restrict__ x,
                                                  short* __restrict__ y,
                                                  const short* __restrict__ Pd,
                                                  const float* __restrict__ db,
                                                  int nnodes, int ntiles) {
    __shared__ short Xs[2][4 * FSLAB];
    const int t = threadIdx.x;
    const int lane = t & 63, w = t >> 6;
    const int ch = blockIdx.x & 1;
    const int cw = ch * 4 + w;
    const int ml = lane & 15, kq = lane >> 4;
    const int col = cw * 16 + ml;
    const float bias = db[col];

    bf16x8 B[4];
    #pragma unroll
    for (int k0 = 0; k0 < 4; ++k0)
        B[k0] = *(const bf16x8*)(Pd + ((size_t)(cw * 4 + k0) * 64 + lane) * 8);

    const int srow = t >> 4, sc8 = t & 15;
    const int soff = (sc8 >> 2) * FSLAB + (srow * 4 + (sc8 & 3)) * 8;
    const int roff = (ml * 4 + kq) * 8;

    const int rt0 = blockIdx.x >> 1;
    const int stride = gridDim.x >> 1;

    {
        int node = rt0 * 16 + srow;
        bf16x8 xv = (bf16x8){0,0,0,0,0,0,0,0};
        if (node < nnodes) xv = *(const bf16x8*)(x + (size_t)node * HID + sc8 * 8);
        *(bf16x8*)&Xs[0][soff] = xv;
    }
    __syncthreads();

    int buf = 0;
    for (int rt = rt0; rt < ntiles; rt += stride, buf ^= 1) {
        const int nrt = rt + stride;
        bf16x8 px = (bf16x8){0,0,0,0,0,0,0,0};
        if (nrt < ntiles) {
            int node = nrt * 16 + srow;
            if (node < nnodes) px = *(const bf16x8*)(x + (size_t)node * HID + sc8 * 8);
        }

        f32x4 acc = (f32x4){0.f, 0.f, 0.f, 0.f};
        #pragma unroll
        for (int k0 = 0; k0 < 4; ++k0) {
            bf16x8 aa = *(const bf16x8*)&Xs[buf][k0 * FSLAB + roff];
            acc = __builtin_amdgcn_mfma_f32_16x16x32_bf16(aa, B[k0], acc, 0, 0, 0);
        }

        const int mbase = rt * 16;
        #pragma unroll
        for (int r = 0; r < 4; ++r) {
            const int node = mbase + kq * 4 + r;
            if (node < nnodes)
                y[(size_t)node * HID + col] = f2bf(acc[r] + bias);
        }

        if (nrt < ntiles) *(bf16x8*)&Xs[buf ^ 1][soff] = px;
        __syncthreads();
    }
}

// ---------------- segment max pool, 4-way split per graph ----------------
__global__ __launch_bounds__(256) void pool_k(const short* __restrict__ xh,
                                              const int* __restrict__ batch,
                                              int nnodes, float* __restrict__ pmax) {
    const int g = blockIdx.x >> 2;
    const int p = blockIdx.x & (POOL_P - 1);
    int lo = 0, hi = nnodes;
    while (lo < hi) { int mid = (lo + hi) >> 1; if (batch[mid] < g) lo = mid + 1; else hi = mid; }
    int start = lo;
    lo = 0; hi = nnodes;
    while (lo < hi) { int mid = (lo + hi) >> 1; if (batch[mid] < g + 1) lo = mid + 1; else hi = mid; }
    int end = lo;
    int len = end - start;
    int q0 = start + (int)(((long long)len * p) / POOL_P);
    int q1 = start + (int)(((long long)len * (p + 1)) / POOL_P);

    const int rg = threadIdx.x >> 6;
    const int j2 = threadIdx.x & 63;
    float m0 = -INFINITY, m1 = -INFINITY;
    for (int i = q0 + rg; i < q1; i += 4) {
        unsigned int u = *(const unsigned int*)(xh + (size_t)i * HID + j2 * 2);
        m0 = fmaxf(m0, __uint_as_float(u << 16));
        m1 = fmaxf(m1, __uint_as_float(u & 0xFFFF0000u));
    }
    __shared__ float pm[4][130];
    pm[rg][j2 * 2] = m0;
    pm[rg][j2 * 2 + 1] = m1;
    __syncthreads();
    if (rg == 0) {
        float a = fmaxf(fmaxf(pm[0][j2 * 2], pm[1][j2 * 2]), fmaxf(pm[2][j2 * 2], pm[3][j2 * 2]));
        float c = fmaxf(fmaxf(pm[0][j2 * 2 + 1], pm[1][j2 * 2 + 1]), fmaxf(pm[2][j2 * 2 + 1], pm[3][j2 * 2 + 1]));
        *(float2*)(pmax + (size_t)blockIdx.x * HID + j2 * 2) = make_float2(a, c);
    }
}

// ---------------- classifier ----------------
__global__ __launch_bounds__(128) void clf_k(const float* __restrict__ pmax,
                                             const float* __restrict__ W,
                                             const float* __restrict__ b,
                                             float* __restrict__ out) {
    __shared__ float red[2];
    const int g = blockIdx.x;
    const int t = threadIdx.x;
    float m = -INFINITY;
    #pragma unroll
    for (int p = 0; p < POOL_P; ++p)
        m = fmaxf(m, pmax[((size_t)g * POOL_P + p) * HID + t]);
    float v = m * W[t];
    #pragma unroll
    for (int off = 32; off >= 1; off >>= 1) v += __shfl_down(v, off, 64);
    if ((t & 63) == 0) red[t >> 6] = v;
    __syncthreads();
    if (t == 0) {
        float s = red[0] + red[1] + b[0];
        out[g] = 1.f / (1.f + expf(-s));
    }
}

extern "C" void kernel_launch(void* const* d_in, const int* in_sizes, int n_in,
                              void* d_out, int out_size, void* d_ws, size_t ws_size,
                              hipStream_t stream) {
    const int* x      = (const int*)d_in[0];
    const int* ei     = (const int*)d_in[1];
    const int* batch  = (const int*)d_in[2];
    const float* emb  = (const float*)d_in[3];
    const float* Wih0 = (const float*)d_in[4];
    const float* Whh0 = (const float*)d_in[5];
    const float* bih0 = (const float*)d_in[6];
    const float* bhh0 = (const float*)d_in[7];
    const float* Wih1 = (const float*)d_in[8];
    const float* Whh1 = (const float*)d_in[9];
    const float* bih1 = (const float*)d_in[10];
    const float* bhh1 = (const float*)d_in[11];
    const float* dW   = (const float*)d_in[12];
    const float* db   = (const float*)d_in[13];
    const float* cW   = (const float*)d_in[14];
    const float* cb   = (const float*)d_in[15];

    const int N = in_sizes[0];          // 100000
    const int E = in_sizes[1] / 2;      // 1600000
    const int NG = out_size;            // 128
    const size_t NH = (size_t)N * HID;
    const int NPB = (N + NPART - 1) / NPART;
    const int ECH = (E + NCHUNK - 1) / NCHUNK;

    short* hb0 = (short*)d_ws;                        // NH bf16
    short* hb1 = hb0 + NH;                            // NH bf16 (agg)
    short* hb2 = hb1 + NH;                            // NH bf16
    short* P0  = hb2 + NH;
    short* P1  = P0 + 48 * 4 * 64 * 8;
    short* Pd  = P1 + 48 * 4 * 64 * 8;
    float* pmax = (float*)(Pd + 8 * 4 * 64 * 8);      // NG*POOL_P*HID
    int* bflag      = (int*)(pmax + (size_t)NG * POOL_P * HID);  // 64
    int* bsum       = bflag + 64;                     // 64
    int* degsum     = bsum + 64;                      // N
    int* rowstart   = degsum + N;                     // N+4
    int* ghist      = rowstart + (N + 4);             // NPART*NCHUNK*NPB
    int* sorted_src = ghist + (size_t)NPART * NCHUNK * NPB;  // E

    const int* esrc = ei;
    const int* edst = ei + E;

    dim3 blk(256);
    int embGrid256  = (N * 16 + 255) / 256;
    int embGrid1024 = (N * 16 + 1023) / 1024;
    int ntiles = (N + 15) / 16;
    const int scanBlocks = (N + 4095) / 4096;   // 25 <= 64
    const int NB = 768;                         // row-loop grid (2 col-halves x 384)

    // weight packing
    pack_all_k<<<104, blk, 0, stream>>>(Wih0, Whh0, Wih1, Whh1, dW, P0, P1, Pd);

    // embed + LDS radix histogram (zero global atomics)
    hipMemsetAsync(bflag, 0, 64 * sizeof(int), stream);
    radix_embed_k<<<NPART * NCHUNK + embGrid1024, dim3(1024), 0, stream>>>(
        x, emb, hb0, N, edst, ghist, E, NPB, ECH);

    // per-node chunk bases + degree, then lookback scan, then LDS-cursor fill
    chunksum_k<<<(N + 255) / 256, blk, 0, stream>>>(ghist, degsum, N, NPB);
    scan_k<<<scanBlocks, dim3(1024), 0, stream>>>(degsum, rowstart, N, bsum, bflag, scanBlocks);
    fill2_k<<<NPART * NCHUNK, dim3(1024), 0, stream>>>(esrc, edst, rowstart, ghist, sorted_src,
                                                       E, N, NPB, ECH);

    // layer 0
    gather_k<<<embGrid256, blk, 0, stream>>>(rowstart, sorted_src, hb0, hb1, N);
    gru_rl_k<<<NB, blk, 0, stream>>>(hb1, hb0, hb2, P0, bih0, bhh0, N, ntiles);

    // layer 1
    gather_k<<<embGrid256, blk, 0, stream>>>(rowstart, sorted_src, hb2, hb1, N);
    gru_rl_k<<<NB, blk, 0, stream>>>(hb1, hb2, hb0, P1, bih1, bhh1, N, ntiles);

    // dense
    dense_rl_k<<<NB, blk, 0, stream>>>(hb0, hb2, Pd, db, N, ntiles);

    // pool + classifier
    pool_k<<<NG * POOL_P, blk, 0, stream>>>(hb2, batch, N, pmax);
    clf_k<<<NG, dim3(128), 0, stream>>>(pmax, cW, cb, (float*)d_out);
}

// Round 12
// 399.575 us; speedup vs baseline: 1.4413x; 1.0001x over previous
//
#include <hip/hip_runtime.h>
#include <hip/hip_bf16.h>
#include <math.h>

#define HID 128
#define POOL_P 4
#define NPART 8
#define NCHUNK 32
#define MAXBIN 12544   // LDS bins per partition (>= ceil(N/8)); 50.2 KB
#define FSLAB 520      // fragment slab stride in shorts (512 + 8 pad)

typedef __attribute__((ext_vector_type(8))) short bf16x8;
typedef __attribute__((ext_vector_type(4))) float f32x4;
typedef __attribute__((ext_vector_type(4))) int int4v;

__device__ __forceinline__ short f2bf(float f) {
    unsigned int u = __float_as_uint(f);
    u += 0x7FFF + ((u >> 16) & 1);   // RNE
    return (short)(u >> 16);
}
__device__ __forceinline__ float bf2f(short s) {
    return __uint_as_float(((unsigned int)(unsigned short)s) << 16);
}

// raw-transcendental gate math
__device__ __forceinline__ float fexp2(float x) {
    float r;
    asm("v_exp_f32 %0, %1\n\ts_nop 0" : "=v"(r) : "v"(x));
    return r;
}
__device__ __forceinline__ float frcp(float x) {
    float r;
    asm("v_rcp_f32 %0, %1\n\ts_nop 0" : "=v"(r) : "v"(x));
    return r;
}
__device__ __forceinline__ float fsigmoid(float x) {
    return frcp(1.f + fexp2(-1.44269504f * x));
}
__device__ __forceinline__ float ftanh(float x) {
    return 1.f - 2.f * frcp(1.f + fexp2(2.88539008f * x));
}

// ------- mega front-end (1024 thr): hist blocks + pack blocks + embed blocks -------
// blocks [0,256): per-(part,chunk) LDS histograms of dst
// blocks [256,360): weight packing (104 tiles); block 256 also zeroes bflag
// blocks [360,...): embedding gather
__global__ __launch_bounds__(1024) void front_k(const int* __restrict__ x,
                                                const float* __restrict__ emb,
                                                short* __restrict__ h, int nnodes,
                                                const int* __restrict__ dst,
                                                int* __restrict__ ghist,
                                                int nedges, int NPB, int ECH,
                                                const float* __restrict__ Wih0,
                                                const float* __restrict__ Whh0,
                                                const float* __restrict__ Wih1,
                                                const float* __restrict__ Whh1,
                                                const float* __restrict__ dW,
                                                short* __restrict__ P0,
                                                short* __restrict__ P1,
                                                short* __restrict__ Pd,
                                                int* __restrict__ bflag) {
    __shared__ int lh[MAXBIN];
    const int t = threadIdx.x;
    if ((int)blockIdx.x < NPART * NCHUNK) {
        const int part = blockIdx.x & (NPART - 1);
        const int chunk = blockIdx.x >> 3;
        const int lo = part * NPB;
        const int hi = min(lo + NPB, nnodes);
        const int nb = hi - lo;
        for (int b = t; b < nb; b += 1024) lh[b] = 0;
        __syncthreads();
        const int e0 = chunk * ECH;
        const int e1 = min(nedges, e0 + ECH);
        for (int base = e0; base < e1; base += 4096) {
            int e = base + (t << 2);
            if (e + 4 <= e1) {
                int4v d4 = *(const int4v*)(dst + e);
                #pragma unroll
                for (int k = 0; k < 4; ++k) {
                    int d = d4[k];
                    if (d >= lo && d < hi) atomicAdd(&lh[d - lo], 1);
                }
            } else {
                for (int k = 0; k < 4 && e + k < e1; ++k) {
                    int d = dst[e + k];
                    if (d >= lo && d < hi) atomicAdd(&lh[d - lo], 1);
                }
            }
        }
        __syncthreads();
        int* out = ghist + (size_t)blockIdx.x * NPB;
        for (int b = t; b < nb; b += 1024) out[b] = lh[b];
    } else if ((int)blockIdx.x < NPART * NCHUNK + 104) {
        // weight packing: 4 tiles per block (1024 thr = 4 x 256-thread tile groups)
        const int bp = blockIdx.x - NPART * NCHUNK;
        if (bp == 0 && t < 64) bflag[t] = 0;
        const int tile_g = t >> 8;          // unused: one tile per block, 256 active
        (void)tile_g;
        if (t >= 256) return;
        int b = bp;
        const float* WA; const float* WB; short* P; int ntilesA; int tile;
        if (b < 48)      { WA = Wih0; WB = Whh0; P = P0; ntilesA = 24; tile = b; }
        else if (b < 96) { WA = Wih1; WB = Whh1; P = P1; ntilesA = 24; tile = b - 48; }
        else             { WA = dW;   WB = dW;   P = Pd; ntilesA = 8;  tile = b - 96; }
        const int lane = t & 63, k0 = t >> 6;
        const float* W;
        int row;
        if (tile < ntilesA) { W = WA; row = tile * 16 + (lane & 15); }
        else                { W = WB; row = (tile - ntilesA) * 16 + (lane & 15); }
        const int k = k0 * 32 + (lane >> 4) * 8;
        const float4 f0 = *(const float4*)(W + row * HID + k);
        const float4 f1 = *(const float4*)(W + row * HID + k + 4);
        short4 o0 = make_short4(f2bf(f0.x), f2bf(f0.y), f2bf(f0.z), f2bf(f0.w));
        short4 o1 = make_short4(f2bf(f1.x), f2bf(f1.y), f2bf(f1.z), f2bf(f1.w));
        short* dstp = P + ((size_t)(tile * 4 + k0) * 64 + lane) * 8;
        *(short4*)(dstp) = o0;
        *(short4*)(dstp + 4) = o1;
    } else {
        int bi = blockIdx.x - (NPART * NCHUNK + 104);
        int tid = bi * 1024 + t;
        int node = tid >> 4;
        int c8 = tid & 15;
        if (node >= nnodes) return;
        int tok = x[node];
        float4 f0 = ((const float4*)emb)[(size_t)tok * 32 + c8 * 2];
        float4 f1 = ((const float4*)emb)[(size_t)tok * 32 + c8 * 2 + 1];
        bf16x8 o;
        o[0] = f2bf(f0.x); o[1] = f2bf(f0.y); o[2] = f2bf(f0.z); o[3] = f2bf(f0.w);
        o[4] = f2bf(f1.x); o[5] = f2bf(f1.y); o[6] = f2bf(f1.z); o[7] = f2bf(f1.w);
        *(bf16x8*)(h + (size_t)node * HID + c8 * 8) = o;
    }
}

// ------- per-node chunk-exclusive prefix (in place) + total degree -------
__global__ __launch_bounds__(256) void chunksum_k(int* __restrict__ ghist,
                                                  int* __restrict__ degsum,
                                                  int nnodes, int NPB) {
    int node = blockIdx.x * 256 + threadIdx.x;
    if (node >= nnodes) return;
    int part = node / NPB;
    int bin = node - part * NPB;
    int running = 0;
    #pragma unroll 4
    for (int c = 0; c < NCHUNK; ++c) {
        size_t idx = (size_t)(part + NPART * c) * NPB + bin;
        int v = ghist[idx];
        ghist[idx] = running;
        running += v;
    }
    degsum[node] = running;
}

// ------- decoupled-lookback exclusive scan over degsum (blocks <= 64) -------
__global__ __launch_bounds__(1024) void scan_k(const int* __restrict__ deg,
                                               int* __restrict__ rowstart,
                                               int n, int* bsum, int* bflag, int nblocks) {
    __shared__ int wsum[16];
    __shared__ int prefix_s, total_s;
    const int b = blockIdx.x;
    const int t = threadIdx.x, lane = t & 63, w = t >> 6;
    const int i4 = b * 4096 + t * 4;
    int4 v = make_int4(0, 0, 0, 0);
    if (i4 + 3 < n) v = *(const int4*)(deg + i4);
    else if (i4 < n) {
        v.x = deg[i4];
        if (i4 + 1 < n) v.y = deg[i4 + 1];
        if (i4 + 2 < n) v.z = deg[i4 + 2];
    }
    int s1 = v.x + v.y, s2 = s1 + v.z, s3 = s2 + v.w;
    int sum = s3;
    #pragma unroll
    for (int off = 1; off < 64; off <<= 1) {
        int o = __shfl_up(sum, off, 64);
        if (lane >= off) sum += o;
    }
    if (lane == 63) wsum[w] = sum;
    __syncthreads();
    if (t == 0) {
        int run = 0;
        #pragma unroll
        for (int k = 0; k < 16; ++k) { int xx = wsum[k]; wsum[k] = run; run += xx; }
        total_s = run;
        atomicExch(&bsum[b], run);
        __threadfence();
        atomicExch(&bflag[b], 1);
    }
    __syncthreads();
    if (w == 0) {
        int p = 0;
        if (lane < b) {
            while (atomicAdd(&bflag[lane], 0) == 0) {}
            p = atomicAdd(&bsum[lane], 0);
        }
        #pragma unroll
        for (int off = 32; off >= 1; off >>= 1) p += __shfl_down(p, off, 64);
        if (lane == 0) prefix_s = p;
    }
    __syncthreads();
    const int excl = (sum - s3) + wsum[w] + prefix_s;
    if (i4 + 3 < n) {
        *(int4*)(rowstart + i4) = make_int4(excl, excl + v.x, excl + s1, excl + s2);
    } else if (i4 < n) {
        rowstart[i4] = excl;
        if (i4 + 1 < n) rowstart[i4 + 1] = excl + v.x;
        if (i4 + 2 < n) rowstart[i4 + 2] = excl + s1;
    }
    if (b == nblocks - 1 && t == 1023) rowstart[n] = prefix_s + total_s;
}

// ------- fill via LDS cursors (1024 thr): zero global atomics, cached edge reads -------
__global__ __launch_bounds__(1024) void fill2_k(const int* __restrict__ src,
                                                const int* __restrict__ dst,
                                                const int* __restrict__ rowstart,
                                                const int* __restrict__ ghist,
                                                int* __restrict__ sorted_src,
                                                int nedges, int nnodes, int NPB, int ECH) {
    __shared__ int cur[MAXBIN];
    const int t = threadIdx.x;
    const int part = blockIdx.x & (NPART - 1);
    const int chunk = blockIdx.x >> 3;
    const int lo = part * NPB;
    const int hi = min(lo + NPB, nnodes);
    const int nb = hi - lo;
    const int* base = ghist + (size_t)blockIdx.x * NPB;
    for (int b = t; b < nb; b += 1024)
        cur[b] = rowstart[lo + b] + base[b];
    __syncthreads();
    const int e0 = chunk * ECH;
    const int e1 = min(nedges, e0 + ECH);
    for (int bb = e0; bb < e1; bb += 4096) {
        int e = bb + (t << 2);
        if (e + 4 <= e1) {
            int4v d4 = *(const int4v*)(dst + e);
            #pragma unroll
            for (int k = 0; k < 4; ++k) {
                int d = d4[k];
                if (d >= lo && d < hi) {
                    int s = src[e + k];
                    int pos = atomicAdd(&cur[d - lo], 1);   // LDS atomic
                    sorted_src[pos] = s;
                }
            }
        } else {
            for (int k = 0; k < 4 && e + k < e1; ++k) {
                int d = dst[e + k];
                if (d >= lo && d < hi) {
                    int s = src[e + k];
                    int pos = atomicAdd(&cur[d - lo], 1);
                    sorted_src[pos] = s;
                }
            }
        }
    }
}

// ---------------- gather-aggregate (bf16 h), 8-deep MLP ----------------
__global__ __launch_bounds__(256) void gather_k(const int* __restrict__ rowstart,
                                                const int* __restrict__ sorted_src,
                                                const short* __restrict__ h,
                                                short* __restrict__ agg, int nnodes) {
    int tid = blockIdx.x * 256 + threadIdx.x;
    int node = tid >> 4;
    int l = tid & 15;
    if (node >= nnodes) return;
    int beg = rowstart[node];
    int end = rowstart[node + 1];
    const bf16x8* hr = (const bf16x8*)h;
    float a[8];
    #pragma unroll
    for (int i = 0; i < 8; ++i) a[i] = 0.f;
    int e = beg;
    for (; e + 8 <= end; e += 8) {
        bf16x8 v0 = hr[(size_t)sorted_src[e] * 16 + l];
        bf16x8 v1 = hr[(size_t)sorted_src[e + 1] * 16 + l];
        bf16x8 v2 = hr[(size_t)sorted_src[e + 2] * 16 + l];
        bf16x8 v3 = hr[(size_t)sorted_src[e + 3] * 16 + l];
        bf16x8 v4 = hr[(size_t)sorted_src[e + 4] * 16 + l];
        bf16x8 v5 = hr[(size_t)sorted_src[e + 5] * 16 + l];
        bf16x8 v6 = hr[(size_t)sorted_src[e + 6] * 16 + l];
        bf16x8 v7 = hr[(size_t)sorted_src[e + 7] * 16 + l];
        #pragma unroll
        for (int i = 0; i < 8; ++i) a[i] += bf2f(v0[i]);
        #pragma unroll
        for (int i = 0; i < 8; ++i) a[i] += bf2f(v1[i]);
        #pragma unroll
        for (int i = 0; i < 8; ++i) a[i] += bf2f(v2[i]);
        #pragma unroll
        for (int i = 0; i < 8; ++i) a[i] += bf2f(v3[i]);
        #pragma unroll
        for (int i = 0; i < 8; ++i) a[i] += bf2f(v4[i]);
        #pragma unroll
        for (int i = 0; i < 8; ++i) a[i] += bf2f(v5[i]);
        #pragma unroll
        for (int i = 0; i < 8; ++i) a[i] += bf2f(v6[i]);
        #pragma unroll
        for (int i = 0; i < 8; ++i) a[i] += bf2f(v7[i]);
    }
    for (; e + 2 <= end; e += 2) {
        bf16x8 v0 = hr[(size_t)sorted_src[e] * 16 + l];
        bf16x8 v1 = hr[(size_t)sorted_src[e + 1] * 16 + l];
        #pragma unroll
        for (int i = 0; i < 8; ++i) a[i] += bf2f(v0[i]);
        #pragma unroll
        for (int i = 0; i < 8; ++i) a[i] += bf2f(v1[i]);
    }
    if (e < end) {
        bf16x8 v0 = hr[(size_t)sorted_src[e] * 16 + l];
        #pragma unroll
        for (int i = 0; i < 8; ++i) a[i] += bf2f(v0[i]);
    }
    bf16x8 o;
    #pragma unroll
    for (int i = 0; i < 8; ++i) o[i] = f2bf(a[i]);
    *(bf16x8*)(agg + (size_t)node * HID + l * 8) = o;
}

// LDS fragment layout with swizzle: logical slab position pos = q*16 + row
// stored at phi(pos) = row*4 + q -> MFMA lane reads conflict-free,
// staging write 2-way only (free).

// ------- GRU row-loop kernel: B fragments in registers, double-buffered LDS -------
__global__ __launch_bounds__(256) void gru_rl_k(const short* __restrict__ agg,
                                                const short* __restrict__ hin,
                                                short* __restrict__ hout,
                                                const short* __restrict__ P,
                                                const float* __restrict__ bih,
                                                const float* __restrict__ bhh,
                                                int nnodes, int ntiles) {
    __shared__ short As[2][4 * FSLAB];
    __shared__ short Hs[2][4 * FSLAB];
    const int t = threadIdx.x;
    const int lane = t & 63, w = t >> 6;
    const int ch = blockIdx.x & 1;
    const int cw = ch * 4 + w;          // col-wave 0..7
    const int ml = lane & 15, kq = lane >> 4;
    const int col = cw * 16 + ml;

    const float b_ir = bih[col], b_iz = bih[col + 128], b_in = bih[col + 256];
    const float b_hr = bhh[col], b_hz = bhh[col + 128], b_hn = bhh[col + 256];

    bf16x8 B[2][3][4];
    #pragma unroll
    for (int m = 0; m < 2; ++m)
        #pragma unroll
        for (int g = 0; g < 3; ++g)
            #pragma unroll
            for (int k0 = 0; k0 < 4; ++k0)
                B[m][g][k0] = *(const bf16x8*)(P +
                    ((size_t)((m * 24 + g * 8 + cw) * 4 + k0) * 64 + lane) * 8);

    const int srow = t >> 4, sc8 = t & 15;
    const int soff = (sc8 >> 2) * FSLAB + (srow * 4 + (sc8 & 3)) * 8;  // phi-swizzled
    const int roff = (ml * 4 + kq) * 8;                                // phi(l)
    const int hoff = (col >> 5) * FSLAB + ((col >> 3) & 3) * 8 + (col & 7);

    const int rt0 = blockIdx.x >> 1;
    const int stride = gridDim.x >> 1;

    {
        int node = rt0 * 16 + srow;
        bf16x8 a = (bf16x8){0,0,0,0,0,0,0,0}, hh = a;
        if (node < nnodes) {
            a  = *(const bf16x8*)(agg + (size_t)node * HID + sc8 * 8);
            hh = *(const bf16x8*)(hin + (size_t)node * HID + sc8 * 8);
        }
        *(bf16x8*)&As[0][soff] = a;
        *(bf16x8*)&Hs[0][soff] = hh;
    }
    __syncthreads();

    int buf = 0;
    for (int rt = rt0; rt < ntiles; rt += stride, buf ^= 1) {
        const int nrt = rt + stride;
        bf16x8 pa = (bf16x8){0,0,0,0,0,0,0,0}, ph = pa;
        if (nrt < ntiles) {
            int node = nrt * 16 + srow;
            if (node < nnodes) {
                pa = *(const bf16x8*)(agg + (size_t)node * HID + sc8 * 8);
                ph = *(const bf16x8*)(hin + (size_t)node * HID + sc8 * 8);
            }
        }

        f32x4 acc[6];
        #pragma unroll
        for (int i = 0; i < 6; ++i) acc[i] = (f32x4){0.f, 0.f, 0.f, 0.f};
        #pragma unroll
        for (int k0 = 0; k0 < 4; ++k0) {
            bf16x8 aa = *(const bf16x8*)&As[buf][k0 * FSLAB + roff];
            bf16x8 ah = *(const bf16x8*)&Hs[buf][k0 * FSLAB + roff];
            #pragma unroll
            for (int g = 0; g < 3; ++g) {
                acc[g]     = __builtin_amdgcn_mfma_f32_16x16x32_bf16(aa, B[0][g][k0], acc[g], 0, 0, 0);
                acc[3 + g] = __builtin_amdgcn_mfma_f32_16x16x32_bf16(ah, B[1][g][k0], acc[3 + g], 0, 0, 0);
            }
        }

        const int mbase = rt * 16;
        #pragma unroll
        for (int r = 0; r < 4; ++r) {
            const int row = kq * 4 + r;
            const int node = mbase + row;
            float ir = acc[0][r] + b_ir;
            float iz = acc[1][r] + b_iz;
            float in_ = acc[2][r] + b_in;
            float hr = acc[3][r] + b_hr;
            float hz = acc[4][r] + b_hz;
            float hn = acc[5][r] + b_hn;
            float rr = fsigmoid(ir + hr);
            float z  = fsigmoid(iz + hz);
            float n  = ftanh(in_ + rr * hn);
            if (node < nnodes) {
                float hval = bf2f(Hs[buf][hoff + row * 32]);
                hout[(size_t)node * HID + col] = f2bf((1.f - z) * n + z * hval);
            }
        }

        if (nrt < ntiles) {
            *(bf16x8*)&As[buf ^ 1][soff] = pa;
            *(bf16x8*)&Hs[buf ^ 1][soff] = ph;
        }
        __syncthreads();
    }
}

// ------- dense row-loop kernel: y = x @ dW.T + db, B in registers -------
__global__ __launch_bounds__(256) void dense_rl_k(const short* __restrict__ x,
                                                  short* __restrict__ y,
                                                  const short* __restrict__ Pd,
                                                  const float* __restrict__ db,
                                                  int nnodes, int ntiles) {
    __shared__ short Xs[2][4 * FSLAB];
    const int t = threadIdx.x;
    const int lane = t & 63, w = t >> 6;
    const int ch = blockIdx.x & 1;
    const int cw = ch * 4 + w;
    const int ml = lane & 15, kq = lane >> 4;
    const int col = cw * 16 + ml;
    const float bias = db[col];

    bf16x8 B[4];
    #pragma unroll
    for (int k0 = 0; k0 < 4; ++k0)
        B[k0] = *(const bf16x8*)(Pd + ((size_t)(cw * 4 + k0) * 64 + lane) * 8);

    const int srow = t >> 4, sc8 = t & 15;
    const int soff = (sc8 >> 2) * FSLAB + (srow * 4 + (sc8 & 3)) * 8;
    const int roff = (ml * 4 + kq) * 8;

    const int rt0 = blockIdx.x >> 1;
    const int stride = gridDim.x >> 1;

    {
        int node = rt0 * 16 + srow;
        bf16x8 xv = (bf16x8){0,0,0,0,0,0,0,0};
        if (node < nnodes) xv = *(const bf16x8*)(x + (size_t)node * HID + sc8 * 8);
        *(bf16x8*)&Xs[0][soff] = xv;
    }
    __syncthreads();

    int buf = 0;
    for (int rt = rt0; rt < ntiles; rt += stride, buf ^= 1) {
        const int nrt = rt + stride;
        bf16x8 px = (bf16x8){0,0,0,0,0,0,0,0};
        if (nrt < ntiles) {
            int node = nrt * 16 + srow;
            if (node < nnodes) px = *(const bf16x8*)(x + (size_t)node * HID + sc8 * 8);
        }

        f32x4 acc = (f32x4){0.f, 0.f, 0.f, 0.f};
        #pragma unroll
        for (int k0 = 0; k0 < 4; ++k0) {
            bf16x8 aa = *(const bf16x8*)&Xs[buf][k0 * FSLAB + roff];
            acc = __builtin_amdgcn_mfma_f32_16x16x32_bf16(aa, B[k0], acc, 0, 0, 0);
        }

        const int mbase = rt * 16;
        #pragma unroll
        for (int r = 0; r < 4; ++r) {
            const int node = mbase + kq * 4 + r;
            if (node < nnodes)
                y[(size_t)node * HID + col] = f2bf(acc[r] + bias);
        }

        if (nrt < ntiles) *(bf16x8*)&Xs[buf ^ 1][soff] = px;
        __syncthreads();
    }
}

// ---------------- segment max pool, 4-way split per graph ----------------
__global__ __launch_bounds__(256) void pool_k(const short* __restrict__ xh,
                                              const int* __restrict__ batch,
                                              int nnodes, float* __restrict__ pmax) {
    const int g = blockIdx.x >> 2;
    const int p = blockIdx.x & (POOL_P - 1);
    int lo = 0, hi = nnodes;
    while (lo < hi) { int mid = (lo + hi) >> 1; if (batch[mid] < g) lo = mid + 1; else hi = mid; }
    int start = lo;
    lo = 0; hi = nnodes;
    while (lo < hi) { int mid = (lo + hi) >> 1; if (batch[mid] < g + 1) lo = mid + 1; else hi = mid; }
    int end = lo;
    int len = end - start;
    int q0 = start + (int)(((long long)len * p) / POOL_P);
    int q1 = start + (int)(((long long)len * (p + 1)) / POOL_P);

    const int rg = threadIdx.x >> 6;
    const int j2 = threadIdx.x & 63;
    float m0 = -INFINITY, m1 = -INFINITY;
    for (int i = q0 + rg; i < q1; i += 4) {
        unsigned int u = *(const unsigned int*)(xh + (size_t)i * HID + j2 * 2);
        m0 = fmaxf(m0, __uint_as_float(u << 16));
        m1 = fmaxf(m1, __uint_as_float(u & 0xFFFF0000u));
    }
    __shared__ float pm[4][130];
    pm[rg][j2 * 2] = m0;
    pm[rg][j2 * 2 + 1] = m1;
    __syncthreads();
    if (rg == 0) {
        float a = fmaxf(fmaxf(pm[0][j2 * 2], pm[1][j2 * 2]), fmaxf(pm[2][j2 * 2], pm[3][j2 * 2]));
        float c = fmaxf(fmaxf(pm[0][j2 * 2 + 1], pm[1][j2 * 2 + 1]), fmaxf(pm[2][j2 * 2 + 1], pm[3][j2 * 2 + 1]));
        *(float2*)(pmax + (size_t)blockIdx.x * HID + j2 * 2) = make_float2(a, c);
    }
}

// ---------------- classifier ----------------
__global__ __launch_bounds__(128) void clf_k(const float* __restrict__ pmax,
                                             const float* __restrict__ W,
                                             const float* __restrict__ b,
                                             float* __restrict__ out) {
    __shared__ float red[2];
    const int g = blockIdx.x;
    const int t = threadIdx.x;
    float m = -INFINITY;
    #pragma unroll
    for (int p = 0; p < POOL_P; ++p)
        m = fmaxf(m, pmax[((size_t)g * POOL_P + p) * HID + t]);
    float v = m * W[t];
    #pragma unroll
    for (int off = 32; off >= 1; off >>= 1) v += __shfl_down(v, off, 64);
    if ((t & 63) == 0) red[t >> 6] = v;
    __syncthreads();
    if (t == 0) {
        float s = red[0] + red[1] + b[0];
        out[g] = 1.f / (1.f + expf(-s));
    }
}

extern "C" void kernel_launch(void* const* d_in, const int* in_sizes, int n_in,
                              void* d_out, int out_size, void* d_ws, size_t ws_size,
                              hipStream_t stream) {
    const int* x      = (const int*)d_in[0];
    const int* ei     = (const int*)d_in[1];
    const int* batch  = (const int*)d_in[2];
    const float* emb  = (const float*)d_in[3];
    const float* Wih0 = (const float*)d_in[4];
    const float* Whh0 = (const float*)d_in[5];
    const float* bih0 = (const float*)d_in[6];
    const float* bhh0 = (const float*)d_in[7];
    const float* Wih1 = (const float*)d_in[8];
    const float* Whh1 = (const float*)d_in[9];
    const float* bih1 = (const float*)d_in[10];
    const float* bhh1 = (const float*)d_in[11];
    const float* dW   = (const float*)d_in[12];
    const float* db   = (const float*)d_in[13];
    const float* cW   = (const float*)d_in[14];
    const float* cb   = (const float*)d_in[15];

    const int N = in_sizes[0];          // 100000
    const int E = in_sizes[1] / 2;      // 1600000
    const int NG = out_size;            // 128
    const size_t NH = (size_t)N * HID;
    const int NPB = (N + NPART - 1) / NPART;
    const int ECH = (E + NCHUNK - 1) / NCHUNK;

    short* hb0 = (short*)d_ws;                        // NH bf16
    short* hb1 = hb0 + NH;                            // NH bf16 (agg)
    short* hb2 = hb1 + NH;                            // NH bf16
    short* P0  = hb2 + NH;
    short* P1  = P0 + 48 * 4 * 64 * 8;
    short* Pd  = P1 + 48 * 4 * 64 * 8;
    float* pmax = (float*)(Pd + 8 * 4 * 64 * 8);      // NG*POOL_P*HID
    int* bflag      = (int*)(pmax + (size_t)NG * POOL_P * HID);  // 64
    int* bsum       = bflag + 64;                     // 64
    int* degsum     = bsum + 64;                      // N
    int* rowstart   = degsum + N;                     // N+4
    int* ghist      = rowstart + (N + 4);             // NPART*NCHUNK*NPB
    int* sorted_src = ghist + (size_t)NPART * NCHUNK * NPB;  // E

    const int* esrc = ei;
    const int* edst = ei + E;

    dim3 blk(256);
    int embGrid256  = (N * 16 + 255) / 256;
    int embGrid1024 = (N * 16 + 1023) / 1024;
    int ntiles = (N + 15) / 16;
    const int scanBlocks = (N + 4095) / 4096;   // 25 <= 64
    const int NB = 768;                         // row-loop grid (2 col-halves x 384)

    // mega front-end: hist + pack + bflag-zero + embed in one launch
    front_k<<<NPART * NCHUNK + 104 + embGrid1024, dim3(1024), 0, stream>>>(
        x, emb, hb0, N, edst, ghist, E, NPB, ECH,
        Wih0, Whh0, Wih1, Whh1, dW, P0, P1, Pd, bflag);

    // per-node chunk bases + degree, then lookback scan, then LDS-cursor fill
    chunksum_k<<<(N + 255) / 256, blk, 0, stream>>>(ghist, degsum, N, NPB);
    scan_k<<<scanBlocks, dim3(1024), 0, stream>>>(degsum, rowstart, N, bsum, bflag, scanBlocks);
    fill2_k<<<NPART * NCHUNK, dim3(1024), 0, stream>>>(esrc, edst, rowstart, ghist, sorted_src,
                                                       E, N, NPB, ECH);

    // layer 0
    gather_k<<<embGrid256, blk, 0, stream>>>(rowstart, sorted_src, hb0, hb1, N);
    gru_rl_k<<<NB, blk, 0, stream>>>(hb1, hb0, hb2, P0, bih0, bhh0, N, ntiles);

    // layer 1
    gather_k<<<embGrid256, blk, 0, stream>>>(rowstart, sorted_src, hb2, hb1, N);
    gru_rl_k<<<NB, blk, 0, stream>>>(hb1, hb2, hb0, P1, bih1, bhh1, N, ntiles);

    // dense
    dense_rl_k<<<NB, blk, 0, stream>>>(hb0, hb2, Pd, db, N, ntiles);

    // pool + classifier
    pool_k<<<NG * POOL_P, blk, 0, stream>>>(hb2, batch, N, pmax);
    clf_k<<<NG, dim3(128), 0, stream>>>(pmax, cW, cb, (float*)d_out);
}